// Round 8
// baseline (146.320 us; speedup 1.0000x reference)
//
#include <hip/hip_runtime.h>
#include <hip/hip_bf16.h>

// Problem constants
#define BATCH 32
#define NTOK 1024          // 32x32
#define CH 256
#define HEADS 8
#define HD 32
#define AGENTS 49
#define WIN 32
#define QKV_N 768
#define SCALE 0.17677669529663687f   // 1/sqrt(32)

typedef unsigned short u16;
typedef __attribute__((ext_vector_type(8))) unsigned short u16x8;
typedef __attribute__((ext_vector_type(8))) short short8;
typedef __attribute__((ext_vector_type(4))) float f32x4;

__device__ __forceinline__ void gload_lds16(const void* g, const void* l) {
    __builtin_amdgcn_global_load_lds(
        (const __attribute__((address_space(1))) unsigned int*)g,
        (__attribute__((address_space(3))) unsigned int*)l, 16, 0, 0);
}

__device__ __forceinline__ u16 f2bf1(float f) {
    unsigned u = __builtin_bit_cast(unsigned, f);
    u += 0x7fffu + ((u >> 16) & 1u);
    return (u16)(u >> 16);
}
__device__ __forceinline__ float bf2f(u16 v) {
    unsigned u = ((unsigned)v) << 16;
    return __builtin_bit_cast(float, u);
}

// ---------------- fp32 -> bf16 conversion, 8 elems/thread ----------------
__global__ void f2bf_kernel(const float* __restrict__ in, u16* __restrict__ out, int n8) {
    int i = blockIdx.x * 256 + threadIdx.x;
    if (i >= n8) return;
    float4 v0 = ((const float4*)in)[i * 2];
    float4 v1 = ((const float4*)in)[i * 2 + 1];
    u16x8 o;
    o[0] = f2bf1(v0.x); o[1] = f2bf1(v0.y); o[2] = f2bf1(v0.z); o[3] = f2bf1(v0.w);
    o[4] = f2bf1(v1.x); o[5] = f2bf1(v1.y); o[6] = f2bf1(v1.z); o[7] = f2bf1(v1.w);
    ((u16x8*)out)[i] = o;
}

// ---------------- bf16 MFMA GEMM: C[M,N] = A[M,K] @ B[N,K]^T (+bias) ----------------
__global__ __launch_bounds__(256) void gemm_bf16(const u16* __restrict__ A,
                                                 const u16* __restrict__ B,
                                                 float* __restrict__ C,
                                                 u16* __restrict__ C16,
                                                 int M, int N, int K,
                                                 const float* __restrict__ bias,
                                                 int amode) {
    __shared__ u16 As[128 * 32];
    __shared__ u16 Bs[128 * 32];
    const int tid = threadIdx.x;
    const int lane = tid & 63;
    const int wid = tid >> 6;
    const int row0 = blockIdx.x * 128, col0 = blockIdx.y * 128;
    const int wr = wid >> 1, wc = wid & 1;
    const int fr = lane & 15, fq = lane >> 4;

    f32x4 acc[4][4];
#pragma unroll
    for (int m = 0; m < 4; ++m)
#pragma unroll
        for (int n = 0; n < 4; ++n) acc[m][n] = (f32x4)(0.f);

    for (int k0 = 0; k0 < K; k0 += 32) {
#pragma unroll
        for (int r = 0; r < 2; ++r) {
            int trow = (tid >> 2) + r * 64;
            int tcol = (tid & 3) * 8;
            size_t aoff;
            int grow = row0 + trow;
            if (amode == 1) {
                int bb = grow >> 10, nn = grow & 1023;
                aoff = ((size_t)(bb * 1025 + nn + 1)) * 256 + (size_t)(k0 + tcol);
            } else {
                if (grow >= M) grow = M - 1;
                aoff = (size_t)grow * K + (size_t)(k0 + tcol);
            }
            gload_lds16(A + aoff, (const char*)As + wid * 1024 + r * 4096);
            int brow = col0 + trow;
            gload_lds16(B + (size_t)brow * K + (size_t)(k0 + tcol),
                        (const char*)Bs + wid * 1024 + r * 4096);
        }
        __syncthreads();

        short8 af[4], bf[4];
#pragma unroll
        for (int m = 0; m < 4; ++m)
            af[m] = *(const short8*)&As[(wr * 64 + m * 16 + fr) * 32 + fq * 8];
#pragma unroll
        for (int n = 0; n < 4; ++n)
            bf[n] = *(const short8*)&Bs[(wc * 64 + n * 16 + fr) * 32 + fq * 8];
#pragma unroll
        for (int m = 0; m < 4; ++m)
#pragma unroll
            for (int n = 0; n < 4; ++n)
                acc[m][n] = __builtin_amdgcn_mfma_f32_16x16x32_bf16(af[m], bf[n], acc[m][n], 0, 0, 0);
        __syncthreads();
    }

#pragma unroll
    for (int m = 0; m < 4; ++m) {
#pragma unroll
        for (int j = 0; j < 4; ++j) {
            int row = row0 + wr * 64 + m * 16 + fq * 4 + j;
            if (row < M) {
#pragma unroll
                for (int n = 0; n < 4; ++n) {
                    int col = col0 + wc * 64 + n * 16 + fr;
                    float v = acc[m][n][j];
                    if (bias) v += bias[col];
                    if (C16) C16[(size_t)row * N + col] = f2bf1(v);
                    else     C[(size_t)row * N + col] = v;
                }
            }
        }
    }
}

// ------- adaptive avg pool of q (bf16) -> agents (b,49,256) f32 -------
__global__ __launch_bounds__(256) void pool_kernel(const u16* __restrict__ qkvb,
                                                   float* __restrict__ agents) {
    int b = blockIdx.x / 7, py = blockIdx.x % 7;
    int ch = threadIdx.x;
    int ys = py * 32 / 7, ye = ((py + 1) * 32 + 6) / 7;
    float acc[7];
#pragma unroll
    for (int i = 0; i < 7; ++i) acc[i] = 0.f;
    for (int y = ys; y < ye; ++y) {
        const u16* rowp = qkvb + ((size_t)(b * NTOK + y * 32)) * QKV_N + ch;
#pragma unroll
        for (int PX = 0; PX < 7; ++PX) {
            const int xs = PX * 32 / 7, xe = ((PX + 1) * 32 + 6) / 7;
            float s = 0.f;
            for (int x = xs; x < xe; ++x) s += bf2f(rowp[(size_t)x * QKV_N]);
            acc[PX] += s;
        }
    }
    int rcnt = ye - ys;
#pragma unroll
    for (int PX = 0; PX < 7; ++PX) {
        const int xs = PX * 32 / 7, xe = ((PX + 1) * 32 + 6) / 7;
        agents[((size_t)(b * AGENTS + py * 7 + PX)) * CH + ch] =
            acc[PX] / (float)(rcnt * (xe - xs));
    }
}

// ---------------- bilinear 7x7 sample (half-pixel, clamped) ----------------
__device__ inline float bilin7(const float* __restrict__ m, float sy, float sx) {
    float fy0 = floorf(sy), fx0 = floorf(sx);
    int y0 = (int)fy0, x0 = (int)fx0;
    float fy = sy - fy0, fx = sx - fx0;
    int y0c = min(max(y0, 0), 6), y1c = min(max(y0 + 1, 0), 6);
    int x0c = min(max(x0, 0), 6), x1c = min(max(x0 + 1, 0), 6);
    float v00 = m[y0c * 7 + x0c], v01 = m[y0c * 7 + x1c];
    float v10 = m[y1c * 7 + x0c], v11 = m[y1c * 7 + x1c];
    return (1.f - fy) * ((1.f - fx) * v00 + fx * v01) + fy * ((1.f - fx) * v10 + fx * v11);
}

// pba[h][a][n] = resize(an_bias)[h,a,y,x] + ah_bias[h,a,y] + aw_bias[h,a,x]  (a-major)
__global__ void pb_kernel(const float* __restrict__ an, const float* __restrict__ ahb,
                          const float* __restrict__ awb, float* __restrict__ pba) {
    int h = blockIdx.x / AGENTS, a = blockIdx.x % AGENTS;
    const float* m = an + (h * AGENTS + a) * 49;
    for (int n = threadIdx.x; n < NTOK; n += 256) {
        int y = n >> 5, x = n & 31;
        float v = bilin7(m, (y + 0.5f) * (7.f / 32.f) - 0.5f, (x + 0.5f) * (7.f / 32.f) - 0.5f);
        v += ahb[(h * AGENTS + a) * 32 + y] + awb[(h * AGENTS + a) * 32 + x];
        pba[((size_t)(h * AGENTS + a)) * NTOK + n] = v;
    }
}

// ab[h][n][a] = resize(na_bias)[h,a,y,x] + ha_bias[h,y,a] + wa_bias[h,x,a]   (n-major)
__global__ void ab_kernel(const float* __restrict__ na, const float* __restrict__ hab,
                          const float* __restrict__ wab, float* __restrict__ ab) {
    int idx = blockIdx.x * 256 + threadIdx.x;
    if (idx >= HEADS * NTOK * AGENTS) return;
    int h = idx / (NTOK * AGENTS);
    int r = idx % (NTOK * AGENTS);
    int n = r / AGENTS, a = r % AGENTS;
    int y = n >> 5, x = n & 31;
    const float* m = na + (h * AGENTS + a) * 49;
    float v = bilin7(m, (y + 0.5f) * (7.f / 32.f) - 0.5f, (x + 0.5f) * (7.f / 32.f) - 0.5f);
    v += hab[(h * 32 + y) * AGENTS + a] + wab[(h * 32 + x) * AGENTS + a];
    ab[idx] = v;
}

// ---------------- agent attention (MFMA): softmax(ah*scale @ K^T + pb) @ V ----------------
__global__ __launch_bounds__(512) void agent_attn3(const u16* __restrict__ qkvb,
                                                   const float* __restrict__ agents,
                                                   const float* __restrict__ pba,
                                                   float* __restrict__ agent_v) {
    int b = blockIdx.x >> 3, h = blockIdx.x & 7;
    int tid = threadIdx.x, lane = tid & 63, w = tid >> 6;
    const int fr = lane & 15, fq = lane >> 4;

#define VTP 1038   // V^T row pad: 519 dw, %32=7 -> fr rows on distinct banks
    __shared__ u16 ah_lds[64 * 32];       // 4 KB, scale folded, rows 49..63 zero
    __shared__ u16 Vt[32 * VTP];          // 66.4 KB  V^T [dim][token]
    __shared__ float PO[8][2304];         // 73.7 KB  per-wave: P u16[64][72] then O f32[64][32]
    __shared__ float lsum_lds[8][64];     // 2 KB

    u16*   Pw = (u16*)&PO[w][0];
    float* Ow = &PO[w][0];

    // ---- staging (cooperative) ----
    for (int li = tid; li < 64 * 32; li += 512) {
        int a = li >> 5, d = li & 31;
        float v = (a < AGENTS) ? agents[((size_t)(b * AGENTS + a)) * CH + h * HD + d] * SCALE : 0.f;
        ah_lds[li] = f2bf1(v);
    }
    for (int li = tid; li < NTOK * 4; li += 512) {      // V^T: 1024 tokens x 4 u16x8 groups
        int tok = li >> 2, d8 = (li & 3) * 8;
        u16x8 v = *(const u16x8*)&qkvb[((size_t)(b * NTOK + tok)) * QKV_N + 2 * CH + h * HD + d8];
#pragma unroll
        for (int j = 0; j < 8; ++j) Vt[(d8 + j) * VTP + tok] = v[j];
    }
    __syncthreads();

    // ---- per-wave ----
    short8 ahf[4];
#pragma unroll
    for (int mt = 0; mt < 4; ++mt)
        ahf[mt] = *(const short8*)&ah_lds[(mt * 16 + fr) * 32 + fq * 8];

    float lsum[4][4];
#pragma unroll
    for (int mt = 0; mt < 4; ++mt)
#pragma unroll
        for (int j = 0; j < 4; ++j) lsum[mt][j] = 0.f;
    f32x4 accO[4][2];
#pragma unroll
    for (int mt = 0; mt < 4; ++mt)
#pragma unroll
        for (int ntd = 0; ntd < 2; ++ntd) accO[mt][ntd] = (f32x4)(0.f);

    const float* pbh = pba + (size_t)h * AGENTS * NTOK;

#pragma unroll
    for (int c2 = 0; c2 < 2; ++c2) {
        int tb = w * 128 + c2 * 64;
        short8 kf[4];
#pragma unroll
        for (int nt = 0; nt < 4; ++nt)
            kf[nt] = *(const short8*)&qkvb[((size_t)(b * NTOK + tb + nt * 16 + fr)) * QKV_N + CH + h * HD + fq * 8];

        f32x4 accS[4];
#pragma unroll
        for (int mt = 0; mt < 4; ++mt) {
#pragma unroll
            for (int nt = 0; nt < 4; ++nt)
                accS[nt] = __builtin_amdgcn_mfma_f32_16x16x32_bf16(ahf[mt], kf[nt], (f32x4)(0.f), 0, 0, 0);
#pragma unroll
            for (int j = 0; j < 4; ++j) {
                int a = mt * 16 + fq * 4 + j;
                const float* pbrow = pbh + (size_t)min(a, AGENTS - 1) * NTOK + tb;
#pragma unroll
                for (int nt = 0; nt < 4; ++nt) {
                    float e = __expf(accS[nt][j] + pbrow[nt * 16 + fr]);
                    lsum[mt][j] += e;
                    Pw[a * 72 + nt * 16 + fr] = f2bf1(e);
                }
            }
        }

        asm volatile("s_waitcnt lgkmcnt(0)" ::: "memory");
        __builtin_amdgcn_sched_barrier(0);

        short8 pf[4][2], vf[2][2];
#pragma unroll
        for (int mt = 0; mt < 4; ++mt)
#pragma unroll
            for (int kc = 0; kc < 2; ++kc)
                pf[mt][kc] = *(const short8*)&Pw[(mt * 16 + fr) * 72 + kc * 32 + fq * 8];
#pragma unroll
        for (int ntd = 0; ntd < 2; ++ntd)
#pragma unroll
            for (int kc = 0; kc < 2; ++kc)
                vf[ntd][kc] = *(const short8*)&Vt[(ntd * 16 + fr) * VTP + tb + kc * 32 + fq * 8];

        asm volatile("s_waitcnt lgkmcnt(0)" ::: "memory");
        __builtin_amdgcn_sched_barrier(0);

#pragma unroll
        for (int mt = 0; mt < 4; ++mt)
#pragma unroll
            for (int kc = 0; kc < 2; ++kc)
#pragma unroll
                for (int ntd = 0; ntd < 2; ++ntd)
                    accO[mt][ntd] = __builtin_amdgcn_mfma_f32_16x16x32_bf16(pf[mt][kc], vf[ntd][kc], accO[mt][ntd], 0, 0, 0);
    }

#pragma unroll
    for (int mt = 0; mt < 4; ++mt)
#pragma unroll
        for (int j = 0; j < 4; ++j) {
            float s = lsum[mt][j];
            s += __shfl_xor(s, 1);
            s += __shfl_xor(s, 2);
            s += __shfl_xor(s, 4);
            s += __shfl_xor(s, 8);
            lsum[mt][j] = s;
        }
    if (fr == 0) {
#pragma unroll
        for (int mt = 0; mt < 4; ++mt)
#pragma unroll
            for (int j = 0; j < 4; ++j)
                lsum_lds[w][mt * 16 + fq * 4 + j] = lsum[mt][j];
    }

#pragma unroll
    for (int mt = 0; mt < 4; ++mt)
#pragma unroll
        for (int ntd = 0; ntd < 2; ++ntd)
#pragma unroll
            for (int j = 0; j < 4; ++j)
                Ow[(mt * 16 + fq * 4 + j) * 32 + ntd * 16 + fr] = accO[mt][ntd][j];

    asm volatile("s_waitcnt lgkmcnt(0)" ::: "memory");
    __syncthreads();

    for (int li = tid; li < AGENTS * HD; li += 512) {
        int a = li >> 5, d = li & 31;
        float L = 0.f, o = 0.f;
#pragma unroll
        for (int ww = 0; ww < 8; ++ww) {
            o += PO[ww][a * 32 + d];
            L += lsum_lds[ww][a];
        }
        agent_v[(((size_t)(b * HEADS + h)) * AGENTS + a) * HD + d] = o / L;
    }
#undef VTP
}

// ---- fused q attention (MFMA) + depthwise conv, bf16 output into proj-GEMM input ----
// grid = b*32 + h*4 + ck; 256 threads = 4 waves; wave w owns tokens [ck*256+w*64, +64),
// processed in two 32-token halves (P buffer u16[32][68] per wave keeps LDS <53.3 KB
// -> 3 blocks/CU). dwc is fused into the PV C-layout epilogue: lane owns
// (token = x0+j of y-row y, d = ntd*16+fr); taps read Vs with j-shared vv[3][6].
__global__ __launch_bounds__(256) void q_attn_dwc(const u16* __restrict__ qkvb,
                                                  const float* __restrict__ agents,
                                                  const float* __restrict__ agent_v,
                                                  const float* __restrict__ ab,
                                                  const float* __restrict__ dwc_w,
                                                  const float* __restrict__ dwc_b,
                                                  u16* __restrict__ outbf) {
    int blk = blockIdx.x;
    int b = blk / 32, rem = blk % 32;
    int h = rem / 4, ck = rem % 4;
    int tid = threadIdx.x;
    int w = tid >> 6, lane = tid & 63;
    int fr = lane & 15, fq = lane >> 4;
    int tb = ck * 256 + w * 64;

    __shared__ u16 Vs[10][32][40];       // 25.6 KB V tile + halo rows
    __shared__ u16 ah_lds[64][32];       // 4 KB
    __shared__ u16 avT[32][72];          // 4.6 KB
    __shared__ u16 Pall[4][32 * 68];     // 17.4 KB (per-wave P, 32-token chunks)
    __shared__ float w9[9][32];          // 1.15 KB
    __shared__ float bia[32];

    u16* Pw = &Pall[w][0];

    // ---- staging ----
    for (int li = tid; li < 64 * 32; li += 256) {
        int a = li >> 5, d = li & 31;
        float v = (a < AGENTS) ? agents[((size_t)(b * AGENTS + a)) * CH + h * HD + d] * SCALE : 0.f;
        ah_lds[a][d] = f2bf1(v);
    }
    for (int li = tid; li < 32 * 64; li += 256) {
        int d = li >> 6, a = li & 63;
        float v = (a < AGENTS) ? agent_v[(((size_t)(b * HEADS + h)) * AGENTS + a) * HD + d] : 0.f;
        avT[d][a] = f2bf1(v);
    }
    for (int li = tid; li < 288; li += 256) {
        int t = li >> 5, d = li & 31;
        w9[t][d] = dwc_w[(h * HD + d) * 9 + t];
    }
    if (tid < 32) bia[tid] = dwc_b[h * HD + tid];
    {   // V tile rows yy = ck*8-1 .. ck*8+8, zero-fill OOB
        int y0 = ck * 8 - 1;
#pragma unroll
        for (int it = 0; it < 5; ++it) {
            int c = it * 256 + tid;
            int r = c >> 7;
            int w7 = c & 127;
            int xx = w7 >> 2;
            int d8 = (w7 & 3) * 8;
            int yy = y0 + r;
            u16x8 v = (u16x8)(0);
            if (yy >= 0 && yy < 32)
                v = *(const u16x8*)&qkvb[((size_t)(b * NTOK + yy * 32 + xx)) * QKV_N + 2 * CH + h * HD + d8];
            *(u16x8*)&Vs[r][xx][d8] = v;
        }
    }
    __syncthreads();

    short8 ahf[4];
#pragma unroll
    for (int nt = 0; nt < 4; ++nt)
        ahf[nt] = *(const short8*)&ah_lds[nt * 16 + fr][fq * 8];
    short8 avf[2][2];
#pragma unroll
    for (int ntd = 0; ntd < 2; ++ntd)
#pragma unroll
        for (int kc = 0; kc < 2; ++kc)
            avf[ntd][kc] = *(const short8*)&avT[ntd * 16 + fr][kc * 32 + fq * 8];

    const float* abh = ab + (size_t)h * NTOK * AGENTS;

#pragma unroll
    for (int half = 0; half < 2; ++half) {
        int hb = tb + half * 32;

        // ---- S = Q @ ah^T (MFMA), softmax, P -> LDS (bf16) ----
#pragma unroll
        for (int mt2 = 0; mt2 < 2; ++mt2) {
            int tok = hb + mt2 * 16 + fr;
            short8 qf = *(const short8*)(qkvb + ((size_t)(b * NTOK + tok)) * QKV_N + h * HD + fq * 8);
            f32x4 accS[4];
#pragma unroll
            for (int nt = 0; nt < 4; ++nt)
                accS[nt] = __builtin_amdgcn_mfma_f32_16x16x32_bf16(qf, ahf[nt], (f32x4)(0.f), 0, 0, 0);

            float e[4][4];   // [j][nt]
            float ps[4];
#pragma unroll
            for (int j = 0; j < 4; ++j) ps[j] = 0.f;
#pragma unroll
            for (int j = 0; j < 4; ++j) {
                int tkj = hb + mt2 * 16 + fq * 4 + j;
                const float* abrow = abh + (size_t)tkj * AGENTS;
#pragma unroll
                for (int nt = 0; nt < 4; ++nt) {
                    int a = nt * 16 + fr;
                    float s = accS[nt][j] + abrow[min(a, AGENTS - 1)];
                    float ev = (a < AGENTS) ? __expf(s) : 0.f;
                    e[j][nt] = ev;
                    ps[j] += ev;
                }
            }
#pragma unroll
            for (int j = 0; j < 4; ++j) {
                ps[j] += __shfl_xor(ps[j], 1);
                ps[j] += __shfl_xor(ps[j], 2);
                ps[j] += __shfl_xor(ps[j], 4);
                ps[j] += __shfl_xor(ps[j], 8);
            }
#pragma unroll
            for (int j = 0; j < 4; ++j) {
                float inv = 1.f / ps[j];
                int tl = mt2 * 16 + fq * 4 + j;
#pragma unroll
                for (int nt = 0; nt < 4; ++nt)
                    Pw[tl * 68 + nt * 16 + fr] = f2bf1(e[j][nt] * inv);
            }
        }

        // P writes visible before read-back (wave-local)
        asm volatile("s_waitcnt lgkmcnt(0)" ::: "memory");
        __builtin_amdgcn_sched_barrier(0);

        short8 pf[2][2];
#pragma unroll
        for (int mt2 = 0; mt2 < 2; ++mt2)
#pragma unroll
            for (int kc = 0; kc < 2; ++kc)
                pf[mt2][kc] = *(const short8*)&Pw[(mt2 * 16 + fr) * 68 + kc * 32 + fq * 8];

        // P reads in regs before next half overwrites Pw
        asm volatile("s_waitcnt lgkmcnt(0)" ::: "memory");
        __builtin_amdgcn_sched_barrier(0);

        f32x4 accO[2][2];
#pragma unroll
        for (int mt2 = 0; mt2 < 2; ++mt2)
#pragma unroll
            for (int ntd = 0; ntd < 2; ++ntd) accO[mt2][ntd] = (f32x4)(0.f);
#pragma unroll
        for (int mt2 = 0; mt2 < 2; ++mt2)
#pragma unroll
            for (int kc = 0; kc < 2; ++kc)
#pragma unroll
                for (int ntd = 0; ntd < 2; ++ntd)
                    accO[mt2][ntd] = __builtin_amdgcn_mfma_f32_16x16x32_bf16(pf[mt2][kc], avf[ntd][kc], accO[mt2][ntd], 0, 0, 0);

        // ---- fused dwc + bias + bf16 store (C-layout epilogue) ----
        // lane element: token n = y*32 + x0 + j (y fixed per wave/half), d = ntd*16+fr
        int y = ck * 8 + w * 2 + half;
        int lr = w * 2 + half + 1;         // row in Vs (y - y0)
#pragma unroll
        for (int ntd = 0; ntd < 2; ++ntd) {
            int d = ntd * 16 + fr;
            float wv[9];
#pragma unroll
            for (int t = 0; t < 9; ++t) wv[t] = w9[t][d];
            float bv = bia[d];
#pragma unroll
            for (int mt2 = 0; mt2 < 2; ++mt2) {
                int x0 = mt2 * 16 + fq * 4;
                float vv[3][6];
#pragma unroll
                for (int dy = 0; dy < 3; ++dy)
#pragma unroll
                    for (int k = 0; k < 6; ++k) {
                        int xx = x0 - 1 + k;
                        vv[dy][k] = (xx >= 0 && xx < 32) ? bf2f(Vs[lr - 1 + dy][xx][d]) : 0.f;
                    }
#pragma unroll
                for (int j = 0; j < 4; ++j) {
                    float o = accO[mt2][ntd][j] + bv;
#pragma unroll
                    for (int dy = 0; dy < 3; ++dy)
#pragma unroll
                        for (int dx = 0; dx < 3; ++dx)
                            o = fmaf(wv[dy * 3 + dx], vv[dy][j + dx], o);
                    int n = y * 32 + x0 + j;
                    outbf[((size_t)(b * 1025 + 1 + n)) * CH + h * HD + d] = f2bf1(o);
                }
            }
        }
    }
}

extern "C" void kernel_launch(void* const* d_in, const int* in_sizes, int n_in,
                              void* d_out, int out_size, void* d_ws, size_t ws_size,
                              hipStream_t stream) {
    const float* x      = (const float*)d_in[0];
    const float* qkv_w  = (const float*)d_in[1];
    const float* proj_w = (const float*)d_in[2];
    const float* proj_b = (const float*)d_in[3];
    const float* dwc_w  = (const float*)d_in[4];
    const float* dwc_b  = (const float*)d_in[5];
    const float* an_b   = (const float*)d_in[6];
    const float* ah_b   = (const float*)d_in[7];
    const float* aw_b   = (const float*)d_in[8];
    const float* na_b   = (const float*)d_in[9];
    const float* ha_b   = (const float*)d_in[10];
    const float* wa_b   = (const float*)d_in[11];
    float* out = (float*)d_out;

    float* ws      = (float*)d_ws;
    u16*   qkvb    = (u16*)ws;                 // 25,165,824 u16 (bf16 qkv)
    float* agents  = ws + 12582912;            // 401,408 f
    float* pba     = agents + 401408;          // 401,408 f  (a-major [h][a][n])
    float* ab      = pba + 401408;             // 401,408 f  (n-major [h][n][49])
    float* agent_v = ab + 401408;              // 401,408 f
    u16* xbf  = (u16*)(agent_v + 401408);      // 8,396,800 u16 (x bf16 -> fused bf16 rows)
    u16* qwbf = xbf + 8396800;                 // 196,608 u16
    u16* pwbf = qwbf + 196608;                 // 65,536 u16

    // conversions (xbf rows b*1025 keep bf16 cls tokens for the proj GEMM)
    f2bf_kernel<<<4100, 256, 0, stream>>>(x, xbf, 8396800 / 8);
    f2bf_kernel<<<96, 256, 0, stream>>>(qkv_w, qwbf, 196608 / 8);
    f2bf_kernel<<<32, 256, 0, stream>>>(proj_w, pwbf, 65536 / 8);
    // 1. qkv(bf16) = xs @ qkv_w^T   (M=32768, N=768, K=256)
    gemm_bf16<<<dim3(256, 6), 256, 0, stream>>>(xbf, qwbf, nullptr, qkvb, 32768, 768, 256, nullptr, 1);
    // 2. agent pooling of q
    pool_kernel<<<BATCH * 7, 256, 0, stream>>>(qkvb, agents);
    // 3. position biases
    pb_kernel<<<HEADS * AGENTS, 256, 0, stream>>>(an_b, ah_b, aw_b, pba);
    ab_kernel<<<(HEADS * NTOK * AGENTS + 255) / 256, 256, 0, stream>>>(na_b, ha_b, wa_b, ab);
    // 4. agent attention (MFMA) -> agent_v
    agent_attn3<<<BATCH * HEADS, 512, 0, stream>>>(qkvb, agents, pba, agent_v);
    // 5. fused q attention (MFMA) + dwc -> bf16 rows 1..1024 of xbf
    q_attn_dwc<<<BATCH * HEADS * 4, 256, 0, stream>>>(qkvb, agents, agent_v, ab, dwc_w, dwc_b, xbf);
    // 6. out = fused @ proj_w^T + proj_b  (M=32800, N=256, K=256)
    gemm_bf16<<<dim3(257, 2), 256, 0, stream>>>(xbf, pwbf, out, nullptr, 32800, 256, 256, proj_b, 0);
}

// Round 9
// 135.620 us; speedup vs baseline: 1.0789x; 1.0789x over previous
//
#include <hip/hip_runtime.h>
#include <hip/hip_bf16.h>

// Problem constants
#define BATCH 32
#define NTOK 1024          // 32x32
#define CH 256
#define HEADS 8
#define HD 32
#define AGENTS 49
#define WIN 32
#define QKV_N 768
#define SCALE 0.17677669529663687f   // 1/sqrt(32)

typedef unsigned short u16;
typedef __attribute__((ext_vector_type(8))) unsigned short u16x8;
typedef __attribute__((ext_vector_type(8))) short short8;
typedef __attribute__((ext_vector_type(4))) float f32x4;

__device__ __forceinline__ void gload_lds16(const void* g, const void* l) {
    __builtin_amdgcn_global_load_lds(
        (const __attribute__((address_space(1))) unsigned int*)g,
        (__attribute__((address_space(3))) unsigned int*)l, 16, 0, 0);
}

__device__ __forceinline__ u16 f2bf1(float f) {
    unsigned u = __builtin_bit_cast(unsigned, f);
    u += 0x7fffu + ((u >> 16) & 1u);
    return (u16)(u >> 16);
}
__device__ __forceinline__ float bf2f(u16 v) {
    unsigned u = ((unsigned)v) << 16;
    return __builtin_bit_cast(float, u);
}

// ---------------- fp32 -> bf16 conversion, 8 elems/thread ----------------
__global__ void f2bf_kernel(const float* __restrict__ in, u16* __restrict__ out, int n8) {
    int i = blockIdx.x * 256 + threadIdx.x;
    if (i >= n8) return;
    float4 v0 = ((const float4*)in)[i * 2];
    float4 v1 = ((const float4*)in)[i * 2 + 1];
    u16x8 o;
    o[0] = f2bf1(v0.x); o[1] = f2bf1(v0.y); o[2] = f2bf1(v0.z); o[3] = f2bf1(v0.w);
    o[4] = f2bf1(v1.x); o[5] = f2bf1(v1.y); o[6] = f2bf1(v1.z); o[7] = f2bf1(v1.w);
    ((u16x8*)out)[i] = o;
}

// ---------------- bf16 MFMA GEMM: C[M,N] = A[M,K] @ B[N,K]^T (+bias) ----------------
__global__ __launch_bounds__(256) void gemm_bf16(const u16* __restrict__ A,
                                                 const u16* __restrict__ B,
                                                 float* __restrict__ C,
                                                 u16* __restrict__ C16,
                                                 int M, int N, int K,
                                                 const float* __restrict__ bias,
                                                 int amode) {
    __shared__ u16 As[128 * 32];
    __shared__ u16 Bs[128 * 32];
    const int tid = threadIdx.x;
    const int lane = tid & 63;
    const int wid = tid >> 6;
    const int row0 = blockIdx.x * 128, col0 = blockIdx.y * 128;
    const int wr = wid >> 1, wc = wid & 1;
    const int fr = lane & 15, fq = lane >> 4;

    f32x4 acc[4][4];
#pragma unroll
    for (int m = 0; m < 4; ++m)
#pragma unroll
        for (int n = 0; n < 4; ++n) acc[m][n] = (f32x4)(0.f);

    for (int k0 = 0; k0 < K; k0 += 32) {
#pragma unroll
        for (int r = 0; r < 2; ++r) {
            int trow = (tid >> 2) + r * 64;
            int tcol = (tid & 3) * 8;
            size_t aoff;
            int grow = row0 + trow;
            if (amode == 1) {
                int bb = grow >> 10, nn = grow & 1023;
                aoff = ((size_t)(bb * 1025 + nn + 1)) * 256 + (size_t)(k0 + tcol);
            } else {
                if (grow >= M) grow = M - 1;
                aoff = (size_t)grow * K + (size_t)(k0 + tcol);
            }
            gload_lds16(A + aoff, (const char*)As + wid * 1024 + r * 4096);
            int brow = col0 + trow;
            gload_lds16(B + (size_t)brow * K + (size_t)(k0 + tcol),
                        (const char*)Bs + wid * 1024 + r * 4096);
        }
        __syncthreads();

        short8 af[4], bf[4];
#pragma unroll
        for (int m = 0; m < 4; ++m)
            af[m] = *(const short8*)&As[(wr * 64 + m * 16 + fr) * 32 + fq * 8];
#pragma unroll
        for (int n = 0; n < 4; ++n)
            bf[n] = *(const short8*)&Bs[(wc * 64 + n * 16 + fr) * 32 + fq * 8];
#pragma unroll
        for (int m = 0; m < 4; ++m)
#pragma unroll
            for (int n = 0; n < 4; ++n)
                acc[m][n] = __builtin_amdgcn_mfma_f32_16x16x32_bf16(af[m], bf[n], acc[m][n], 0, 0, 0);
        __syncthreads();
    }

#pragma unroll
    for (int m = 0; m < 4; ++m) {
#pragma unroll
        for (int j = 0; j < 4; ++j) {
            int row = row0 + wr * 64 + m * 16 + fq * 4 + j;
            if (row < M) {
#pragma unroll
                for (int n = 0; n < 4; ++n) {
                    int col = col0 + wc * 64 + n * 16 + fr;
                    float v = acc[m][n][j];
                    if (bias) v += bias[col];
                    if (C16) C16[(size_t)row * N + col] = f2bf1(v);
                    else     C[(size_t)row * N + col] = v;
                }
            }
        }
    }
}

// ------- adaptive avg pool of q (bf16) -> agents (b,49,256) f32 -------
__global__ __launch_bounds__(256) void pool_kernel(const u16* __restrict__ qkvb,
                                                   float* __restrict__ agents) {
    int b = blockIdx.x / 7, py = blockIdx.x % 7;
    int ch = threadIdx.x;
    int ys = py * 32 / 7, ye = ((py + 1) * 32 + 6) / 7;
    float acc[7];
#pragma unroll
    for (int i = 0; i < 7; ++i) acc[i] = 0.f;
    for (int y = ys; y < ye; ++y) {
        const u16* rowp = qkvb + ((size_t)(b * NTOK + y * 32)) * QKV_N + ch;
#pragma unroll
        for (int PX = 0; PX < 7; ++PX) {
            const int xs = PX * 32 / 7, xe = ((PX + 1) * 32 + 6) / 7;
            float s = 0.f;
            for (int x = xs; x < xe; ++x) s += bf2f(rowp[(size_t)x * QKV_N]);
            acc[PX] += s;
        }
    }
    int rcnt = ye - ys;
#pragma unroll
    for (int PX = 0; PX < 7; ++PX) {
        const int xs = PX * 32 / 7, xe = ((PX + 1) * 32 + 6) / 7;
        agents[((size_t)(b * AGENTS + py * 7 + PX)) * CH + ch] =
            acc[PX] / (float)(rcnt * (xe - xs));
    }
}

// ---------------- bilinear 7x7 sample (half-pixel, clamped) ----------------
__device__ inline float bilin7(const float* __restrict__ m, float sy, float sx) {
    float fy0 = floorf(sy), fx0 = floorf(sx);
    int y0 = (int)fy0, x0 = (int)fx0;
    float fy = sy - fy0, fx = sx - fx0;
    int y0c = min(max(y0, 0), 6), y1c = min(max(y0 + 1, 0), 6);
    int x0c = min(max(x0, 0), 6), x1c = min(max(x0 + 1, 0), 6);
    float v00 = m[y0c * 7 + x0c], v01 = m[y0c * 7 + x1c];
    float v10 = m[y1c * 7 + x0c], v11 = m[y1c * 7 + x1c];
    return (1.f - fy) * ((1.f - fx) * v00 + fx * v01) + fy * ((1.f - fx) * v10 + fx * v11);
}

// pba[h][a][n] = resize(an_bias)[h,a,y,x] + ah_bias[h,a,y] + aw_bias[h,a,x]  (a-major)
__global__ void pb_kernel(const float* __restrict__ an, const float* __restrict__ ahb,
                          const float* __restrict__ awb, float* __restrict__ pba) {
    int h = blockIdx.x / AGENTS, a = blockIdx.x % AGENTS;
    const float* m = an + (h * AGENTS + a) * 49;
    for (int n = threadIdx.x; n < NTOK; n += 256) {
        int y = n >> 5, x = n & 31;
        float v = bilin7(m, (y + 0.5f) * (7.f / 32.f) - 0.5f, (x + 0.5f) * (7.f / 32.f) - 0.5f);
        v += ahb[(h * AGENTS + a) * 32 + y] + awb[(h * AGENTS + a) * 32 + x];
        pba[((size_t)(h * AGENTS + a)) * NTOK + n] = v;
    }
}

// abT[h][a][n] = resize(na_bias)[h,a,y,x] + ha_bias[h,y,a] + wa_bias[h,x,a]   (a-major)
__global__ void ab_kernel(const float* __restrict__ na, const float* __restrict__ hab,
                          const float* __restrict__ wab, float* __restrict__ abT) {
    int idx = blockIdx.x * 256 + threadIdx.x;          // = (h*49 + a)*1024 + n
    if (idx >= HEADS * AGENTS * NTOK) return;
    int h = idx / (AGENTS * NTOK);
    int r = idx % (AGENTS * NTOK);
    int a = r / NTOK, n = r % NTOK;
    int y = n >> 5, x = n & 31;
    const float* m = na + (h * AGENTS + a) * 49;
    float v = bilin7(m, (y + 0.5f) * (7.f / 32.f) - 0.5f, (x + 0.5f) * (7.f / 32.f) - 0.5f);
    v += hab[(h * 32 + y) * AGENTS + a] + wab[(h * 32 + x) * AGENTS + a];
    abT[idx] = v;
}

// ============ fused attention: agent-attn (MFMA) + q-attn (MFMA) + dwc ============
// grid = 256 (b,h); 512 threads = 8 waves. Phase 1 = agent attention -> avT in LDS.
// Phase 2 = q attention + depthwise conv, V taps and PV B-operand both from the
// phase-1 Vt transpose. Fragment conventions session-verified (gemm_bf16).
#define VTP 1038   // V^T row pad: 519 dw, %32=7 -> fr rows on distinct banks
__global__ __launch_bounds__(512) void fused_attn(const u16* __restrict__ qkvb,
                                                  const float* __restrict__ agents,
                                                  const float* __restrict__ pba,
                                                  const float* __restrict__ abT,
                                                  const float* __restrict__ dwc_w,
                                                  const float* __restrict__ dwc_b,
                                                  u16* __restrict__ outbf) {
    int b = blockIdx.x >> 3, h = blockIdx.x & 7;
    int tid = threadIdx.x, lane = tid & 63, w = tid >> 6;
    const int fr = lane & 15, fq = lane >> 4;

    __shared__ u16 ah_lds[64 * 32];       // 4 KB, scale folded, rows 49..63 zero
    __shared__ u16 Vt[32 * VTP];          // 66.4 KB  V^T [dim][token] (both phases)
    __shared__ float PO[8][2304];         // 73.7 KB  per-wave P/O scratch
    __shared__ float lsum_lds[8][64];     // 2 KB
    __shared__ u16 avT[32][72];           // 4.6 KB  agent_v^T bf16 (phase 2)
    __shared__ float w9[9][32];           // 1.15 KB
    __shared__ float bia[32];

    u16*   Pw = (u16*)&PO[w][0];
    float* Ow = &PO[w][0];

    // ---- staging (cooperative) ----
    for (int li = tid; li < 64 * 32; li += 512) {
        int a = li >> 5, d = li & 31;
        float v = (a < AGENTS) ? agents[((size_t)(b * AGENTS + a)) * CH + h * HD + d] * SCALE : 0.f;
        ah_lds[li] = f2bf1(v);
    }
    for (int li = tid; li < NTOK * 4; li += 512) {      // V^T: 1024 tokens x 4 u16x8 groups
        int tok = li >> 2, d8 = (li & 3) * 8;
        u16x8 v = *(const u16x8*)&qkvb[((size_t)(b * NTOK + tok)) * QKV_N + 2 * CH + h * HD + d8];
#pragma unroll
        for (int j = 0; j < 8; ++j) Vt[(d8 + j) * VTP + tok] = v[j];
    }
    for (int li = tid; li < 288; li += 512) {
        int t = li >> 5, d = li & 31;
        w9[t][d] = dwc_w[(h * HD + d) * 9 + t];
    }
    if (tid < 32) bia[tid] = dwc_b[h * HD + tid];
    __syncthreads();

    // ================= phase 1: agent attention =================
    short8 ahf[4];
#pragma unroll
    for (int mt = 0; mt < 4; ++mt)
        ahf[mt] = *(const short8*)&ah_lds[(mt * 16 + fr) * 32 + fq * 8];

    float lsum[4][4];
#pragma unroll
    for (int mt = 0; mt < 4; ++mt)
#pragma unroll
        for (int j = 0; j < 4; ++j) lsum[mt][j] = 0.f;
    f32x4 accA[4][2];
#pragma unroll
    for (int mt = 0; mt < 4; ++mt)
#pragma unroll
        for (int ntd = 0; ntd < 2; ++ntd) accA[mt][ntd] = (f32x4)(0.f);

    const float* pbh = pba + (size_t)h * AGENTS * NTOK;

#pragma unroll
    for (int c2 = 0; c2 < 2; ++c2) {
        int tb = w * 128 + c2 * 64;
        short8 kf[4];
#pragma unroll
        for (int nt = 0; nt < 4; ++nt)
            kf[nt] = *(const short8*)&qkvb[((size_t)(b * NTOK + tb + nt * 16 + fr)) * QKV_N + CH + h * HD + fq * 8];

        f32x4 accS[4];
#pragma unroll
        for (int mt = 0; mt < 4; ++mt) {
#pragma unroll
            for (int nt = 0; nt < 4; ++nt)
                accS[nt] = __builtin_amdgcn_mfma_f32_16x16x32_bf16(ahf[mt], kf[nt], (f32x4)(0.f), 0, 0, 0);
#pragma unroll
            for (int j = 0; j < 4; ++j) {
                int a = mt * 16 + fq * 4 + j;
                const float* pbrow = pbh + (size_t)min(a, AGENTS - 1) * NTOK + tb;
#pragma unroll
                for (int nt = 0; nt < 4; ++nt) {
                    float e = __expf(accS[nt][j] + pbrow[nt * 16 + fr]);
                    lsum[mt][j] += e;
                    Pw[a * 72 + nt * 16 + fr] = f2bf1(e);
                }
            }
        }

        asm volatile("s_waitcnt lgkmcnt(0)" ::: "memory");
        __builtin_amdgcn_sched_barrier(0);

        short8 pf[4][2], vf[2][2];
#pragma unroll
        for (int mt = 0; mt < 4; ++mt)
#pragma unroll
            for (int kc = 0; kc < 2; ++kc)
                pf[mt][kc] = *(const short8*)&Pw[(mt * 16 + fr) * 72 + kc * 32 + fq * 8];
#pragma unroll
        for (int ntd = 0; ntd < 2; ++ntd)
#pragma unroll
            for (int kc = 0; kc < 2; ++kc)
                vf[ntd][kc] = *(const short8*)&Vt[(ntd * 16 + fr) * VTP + tb + kc * 32 + fq * 8];

        asm volatile("s_waitcnt lgkmcnt(0)" ::: "memory");
        __builtin_amdgcn_sched_barrier(0);

#pragma unroll
        for (int mt = 0; mt < 4; ++mt)
#pragma unroll
            for (int kc = 0; kc < 2; ++kc)
#pragma unroll
                for (int ntd = 0; ntd < 2; ++ntd)
                    accA[mt][ntd] = __builtin_amdgcn_mfma_f32_16x16x32_bf16(pf[mt][kc], vf[ntd][kc], accA[mt][ntd], 0, 0, 0);
    }

#pragma unroll
    for (int mt = 0; mt < 4; ++mt)
#pragma unroll
        for (int j = 0; j < 4; ++j) {
            float s = lsum[mt][j];
            s += __shfl_xor(s, 1);
            s += __shfl_xor(s, 2);
            s += __shfl_xor(s, 4);
            s += __shfl_xor(s, 8);
            lsum[mt][j] = s;
        }
    if (fr == 0) {
#pragma unroll
        for (int mt = 0; mt < 4; ++mt)
#pragma unroll
            for (int j = 0; j < 4; ++j)
                lsum_lds[w][mt * 16 + fq * 4 + j] = lsum[mt][j];
    }

#pragma unroll
    for (int mt = 0; mt < 4; ++mt)
#pragma unroll
        for (int ntd = 0; ntd < 2; ++ntd)
#pragma unroll
            for (int j = 0; j < 4; ++j)
                Ow[(mt * 16 + fq * 4 + j) * 32 + ntd * 16 + fr] = accA[mt][ntd][j];

    asm volatile("s_waitcnt lgkmcnt(0)" ::: "memory");
    __syncthreads();

    // merge 8 waves -> avT (bf16, [d][a], rows a>=49 zero); no global round-trip
    for (int li = tid; li < 64 * HD; li += 512) {
        int a = li & 63, d = li >> 6;
        float val = 0.f;
        if (a < AGENTS) {
            float L = 0.f, o = 0.f;
#pragma unroll
            for (int ww = 0; ww < 8; ++ww) {
                o += PO[ww][a * 32 + d];
                L += lsum_lds[ww][a];
            }
            val = o / L;
        }
        avT[d][a] = f2bf1(val);
    }
    __syncthreads();

    // ================= phase 2: q attention + dwc =================
    short8 avf[2][2];
#pragma unroll
    for (int ntd = 0; ntd < 2; ++ntd)
#pragma unroll
        for (int kc = 0; kc < 2; ++kc)
            avf[ntd][kc] = *(const short8*)&avT[ntd * 16 + fr][kc * 32 + fq * 8];

    const float* abTh = abT + (size_t)h * AGENTS * NTOK;

#pragma unroll
    for (int hh = 0; hh < 4; ++hh) {
        int hb = w * 128 + hh * 32;

        // S = Q @ ah^T, softmax, P -> LDS (32-token chunk, pad 68)
#pragma unroll
        for (int mt2 = 0; mt2 < 2; ++mt2) {
            int tok = hb + mt2 * 16 + fr;
            short8 qf = *(const short8*)(qkvb + ((size_t)(b * NTOK + tok)) * QKV_N + h * HD + fq * 8);
            f32x4 accS[4];
            f32x4 abv[4];
#pragma unroll
            for (int nt = 0; nt < 4; ++nt) {
                accS[nt] = __builtin_amdgcn_mfma_f32_16x16x32_bf16(qf, ahf[nt], (f32x4)(0.f), 0, 0, 0);
                abv[nt] = *(const f32x4*)&abTh[(size_t)min(nt * 16 + fr, AGENTS - 1) * NTOK + hb + mt2 * 16 + fq * 4];
            }

            float e[4][4];   // [j][nt]
            float ps[4];
#pragma unroll
            for (int j = 0; j < 4; ++j) ps[j] = 0.f;
#pragma unroll
            for (int j = 0; j < 4; ++j) {
#pragma unroll
                for (int nt = 0; nt < 4; ++nt) {
                    int a = nt * 16 + fr;
                    float s = accS[nt][j] + abv[nt][j];
                    float ev = (a < AGENTS) ? __expf(s) : 0.f;
                    e[j][nt] = ev;
                    ps[j] += ev;
                }
            }
#pragma unroll
            for (int j = 0; j < 4; ++j) {
                ps[j] += __shfl_xor(ps[j], 1);
                ps[j] += __shfl_xor(ps[j], 2);
                ps[j] += __shfl_xor(ps[j], 4);
                ps[j] += __shfl_xor(ps[j], 8);
            }
#pragma unroll
            for (int j = 0; j < 4; ++j) {
                float inv = 1.f / ps[j];
                int tl = mt2 * 16 + fq * 4 + j;
#pragma unroll
                for (int nt = 0; nt < 4; ++nt)
                    Pw[tl * 68 + nt * 16 + fr] = f2bf1(e[j][nt] * inv);
            }
        }

        asm volatile("s_waitcnt lgkmcnt(0)" ::: "memory");
        __builtin_amdgcn_sched_barrier(0);

        short8 pf2[2][2];
#pragma unroll
        for (int mt2 = 0; mt2 < 2; ++mt2)
#pragma unroll
            for (int kc = 0; kc < 2; ++kc)
                pf2[mt2][kc] = *(const short8*)&Pw[(mt2 * 16 + fr) * 68 + kc * 32 + fq * 8];

        asm volatile("s_waitcnt lgkmcnt(0)" ::: "memory");
        __builtin_amdgcn_sched_barrier(0);

        f32x4 accO[2][2];
#pragma unroll
        for (int mt2 = 0; mt2 < 2; ++mt2)
#pragma unroll
            for (int ntd = 0; ntd < 2; ++ntd) accO[mt2][ntd] = (f32x4)(0.f);
#pragma unroll
        for (int mt2 = 0; mt2 < 2; ++mt2)
#pragma unroll
            for (int kc = 0; kc < 2; ++kc)
#pragma unroll
                for (int ntd = 0; ntd < 2; ++ntd)
                    accO[mt2][ntd] = __builtin_amdgcn_mfma_f32_16x16x32_bf16(pf2[mt2][kc], avf[ntd][kc], accO[mt2][ntd], 0, 0, 0);

        // fused dwc + bias + bf16 store (C-layout epilogue); V taps from Vt
        int y = w * 4 + hh;
#pragma unroll
        for (int ntd = 0; ntd < 2; ++ntd) {
            int d = ntd * 16 + fr;
            float wv[9];
#pragma unroll
            for (int t = 0; t < 9; ++t) wv[t] = w9[t][d];
            float bv = bia[d];
            const u16* Vd = &Vt[d * VTP];
#pragma unroll
            for (int mt2 = 0; mt2 < 2; ++mt2) {
                int x0 = mt2 * 16 + fq * 4;
                float vv[3][6];
#pragma unroll
                for (int dy = 0; dy < 3; ++dy) {
                    int yy = y - 1 + dy;
#pragma unroll
                    for (int k = 0; k < 6; ++k) {
                        int xx = x0 - 1 + k;
                        vv[dy][k] = (yy >= 0 && yy < 32 && xx >= 0 && xx < 32)
                                  ? bf2f(Vd[yy * 32 + xx]) : 0.f;
                    }
                }
#pragma unroll
                for (int j = 0; j < 4; ++j) {
                    float o = accO[mt2][ntd][j] + bv;
#pragma unroll
                    for (int dy = 0; dy < 3; ++dy)
#pragma unroll
                        for (int dx = 0; dx < 3; ++dx)
                            o = fmaf(wv[dy * 3 + dx], vv[dy][j + dx], o);
                    int n = y * 32 + x0 + j;
                    outbf[((size_t)(b * 1025 + 1 + n)) * CH + h * HD + d] = f2bf1(o);
                }
            }
        }
    }
}
#undef VTP

extern "C" void kernel_launch(void* const* d_in, const int* in_sizes, int n_in,
                              void* d_out, int out_size, void* d_ws, size_t ws_size,
                              hipStream_t stream) {
    const float* x      = (const float*)d_in[0];
    const float* qkv_w  = (const float*)d_in[1];
    const float* proj_w = (const float*)d_in[2];
    const float* proj_b = (const float*)d_in[3];
    const float* dwc_w  = (const float*)d_in[4];
    const float* dwc_b  = (const float*)d_in[5];
    const float* an_b   = (const float*)d_in[6];
    const float* ah_b   = (const float*)d_in[7];
    const float* aw_b   = (const float*)d_in[8];
    const float* na_b   = (const float*)d_in[9];
    const float* ha_b   = (const float*)d_in[10];
    const float* wa_b   = (const float*)d_in[11];
    float* out = (float*)d_out;

    float* ws      = (float*)d_ws;
    u16*   qkvb    = (u16*)ws;                 // 25,165,824 u16 (bf16 qkv)
    float* agents  = ws + 12582912;            // 401,408 f
    float* pba     = agents + 401408;          // 401,408 f  (a-major [h][a][n])
    float* abT     = pba + 401408;             // 401,408 f  (a-major [h][a][n])
    float* unused  = abT + 401408;             // 401,408 f  (kept for layout stability)
    u16* xbf  = (u16*)(unused + 401408);       // 8,396,800 u16 (x bf16 -> fused bf16 rows)
    u16* qwbf = xbf + 8396800;                 // 196,608 u16
    u16* pwbf = qwbf + 196608;                 // 65,536 u16

    // conversions (xbf rows b*1025 keep bf16 cls tokens for the proj GEMM)
    f2bf_kernel<<<4100, 256, 0, stream>>>(x, xbf, 8396800 / 8);
    f2bf_kernel<<<96, 256, 0, stream>>>(qkv_w, qwbf, 196608 / 8);
    f2bf_kernel<<<32, 256, 0, stream>>>(proj_w, pwbf, 65536 / 8);
    // 1. qkv(bf16) = xs @ qkv_w^T   (M=32768, N=768, K=256)
    gemm_bf16<<<dim3(256, 6), 256, 0, stream>>>(xbf, qwbf, nullptr, qkvb, 32768, 768, 256, nullptr, 1);
    // 2. agent pooling of q
    pool_kernel<<<BATCH * 7, 256, 0, stream>>>(qkvb, agents);
    // 3. position biases (both a-major)
    pb_kernel<<<HEADS * AGENTS, 256, 0, stream>>>(an_b, ah_b, aw_b, pba);
    ab_kernel<<<(HEADS * AGENTS * NTOK + 255) / 256, 256, 0, stream>>>(na_b, ha_b, wa_b, abT);
    // 4. fused agent-attn + q-attn + dwc -> bf16 rows 1..1024 of xbf
    fused_attn<<<BATCH * HEADS, 512, 0, stream>>>(qkvb, agents, pba, abT, dwc_w, dwc_b, xbf);
    // 5. out = fused @ proj_w^T + proj_b  (M=32800, N=256, K=256)
    gemm_bf16<<<dim3(257, 2), 256, 0, stream>>>(xbf, pwbf, out, nullptr, 32800, 256, 256, proj_b, 0);
}

// Round 10
// 134.243 us; speedup vs baseline: 1.0900x; 1.0103x over previous
//
#include <hip/hip_runtime.h>
#include <hip/hip_bf16.h>

// Problem constants
#define BATCH 32
#define NTOK 1024          // 32x32
#define CH 256
#define HEADS 8
#define HD 32
#define AGENTS 49
#define WIN 32
#define QKV_N 768
#define SCALE 0.17677669529663687f   // 1/sqrt(32)

typedef unsigned short u16;
typedef __attribute__((ext_vector_type(2))) unsigned short u16x2;
typedef __attribute__((ext_vector_type(8))) unsigned short u16x8;
typedef __attribute__((ext_vector_type(8))) short short8;
typedef __attribute__((ext_vector_type(4))) float f32x4;

__device__ __forceinline__ void gload_lds16(const void* g, const void* l) {
    __builtin_amdgcn_global_load_lds(
        (const __attribute__((address_space(1))) unsigned int*)g,
        (__attribute__((address_space(3))) unsigned int*)l, 16, 0, 0);
}

__device__ __forceinline__ u16 f2bf1(float f) {
    unsigned u = __builtin_bit_cast(unsigned, f);
    u += 0x7fffu + ((u >> 16) & 1u);
    return (u16)(u >> 16);
}
__device__ __forceinline__ float bf2f(u16 v) {
    unsigned u = ((unsigned)v) << 16;
    return __builtin_bit_cast(float, u);
}

// ---------------- fp32 -> bf16 conversion, 8 elems/thread ----------------
__global__ void f2bf_kernel(const float* __restrict__ in, u16* __restrict__ out, int n8) {
    int i = blockIdx.x * 256 + threadIdx.x;
    if (i >= n8) return;
    float4 v0 = ((const float4*)in)[i * 2];
    float4 v1 = ((const float4*)in)[i * 2 + 1];
    u16x8 o;
    o[0] = f2bf1(v0.x); o[1] = f2bf1(v0.y); o[2] = f2bf1(v0.z); o[3] = f2bf1(v0.w);
    o[4] = f2bf1(v1.x); o[5] = f2bf1(v1.y); o[6] = f2bf1(v1.z); o[7] = f2bf1(v1.w);
    ((u16x8*)out)[i] = o;
}

// ---------------- bf16 MFMA GEMM: C[M,N] = A[M,K] @ B[N,K]^T (+bias) ----------------
__global__ __launch_bounds__(256) void gemm_bf16(const u16* __restrict__ A,
                                                 const u16* __restrict__ B,
                                                 float* __restrict__ C,
                                                 u16* __restrict__ C16,
                                                 int M, int N, int K,
                                                 const float* __restrict__ bias,
                                                 int amode) {
    __shared__ u16 As[128 * 32];
    __shared__ u16 Bs[128 * 32];
    const int tid = threadIdx.x;
    const int lane = tid & 63;
    const int wid = tid >> 6;
    const int row0 = blockIdx.x * 128, col0 = blockIdx.y * 128;
    const int wr = wid >> 1, wc = wid & 1;
    const int fr = lane & 15, fq = lane >> 4;

    f32x4 acc[4][4];
#pragma unroll
    for (int m = 0; m < 4; ++m)
#pragma unroll
        for (int n = 0; n < 4; ++n) acc[m][n] = (f32x4)(0.f);

    for (int k0 = 0; k0 < K; k0 += 32) {
#pragma unroll
        for (int r = 0; r < 2; ++r) {
            int trow = (tid >> 2) + r * 64;
            int tcol = (tid & 3) * 8;
            size_t aoff;
            int grow = row0 + trow;
            if (amode == 1) {
                int bb = grow >> 10, nn = grow & 1023;
                aoff = ((size_t)(bb * 1025 + nn + 1)) * 256 + (size_t)(k0 + tcol);
            } else {
                if (grow >= M) grow = M - 1;
                aoff = (size_t)grow * K + (size_t)(k0 + tcol);
            }
            gload_lds16(A + aoff, (const char*)As + wid * 1024 + r * 4096);
            int brow = col0 + trow;
            gload_lds16(B + (size_t)brow * K + (size_t)(k0 + tcol),
                        (const char*)Bs + wid * 1024 + r * 4096);
        }
        __syncthreads();

        short8 af[4], bf[4];
#pragma unroll
        for (int m = 0; m < 4; ++m)
            af[m] = *(const short8*)&As[(wr * 64 + m * 16 + fr) * 32 + fq * 8];
#pragma unroll
        for (int n = 0; n < 4; ++n)
            bf[n] = *(const short8*)&Bs[(wc * 64 + n * 16 + fr) * 32 + fq * 8];
#pragma unroll
        for (int m = 0; m < 4; ++m)
#pragma unroll
            for (int n = 0; n < 4; ++n)
                acc[m][n] = __builtin_amdgcn_mfma_f32_16x16x32_bf16(af[m], bf[n], acc[m][n], 0, 0, 0);
        __syncthreads();
    }

#pragma unroll
    for (int m = 0; m < 4; ++m) {
#pragma unroll
        for (int j = 0; j < 4; ++j) {
            int row = row0 + wr * 64 + m * 16 + fq * 4 + j;
            if (row < M) {
#pragma unroll
                for (int n = 0; n < 4; ++n) {
                    int col = col0 + wc * 64 + n * 16 + fr;
                    float v = acc[m][n][j];
                    if (bias) v += bias[col];
                    if (C16) C16[(size_t)row * N + col] = f2bf1(v);
                    else     C[(size_t)row * N + col] = v;
                }
            }
        }
    }
}

// ------- adaptive avg pool of q (bf16) -> agents (b,49,256) f32 -------
__global__ __launch_bounds__(256) void pool_kernel(const u16* __restrict__ qkvb,
                                                   float* __restrict__ agents) {
    int b = blockIdx.x / 7, py = blockIdx.x % 7;
    int ch = threadIdx.x;
    int ys = py * 32 / 7, ye = ((py + 1) * 32 + 6) / 7;
    float acc[7];
#pragma unroll
    for (int i = 0; i < 7; ++i) acc[i] = 0.f;
    for (int y = ys; y < ye; ++y) {
        const u16* rowp = qkvb + ((size_t)(b * NTOK + y * 32)) * QKV_N + ch;
#pragma unroll
        for (int PX = 0; PX < 7; ++PX) {
            const int xs = PX * 32 / 7, xe = ((PX + 1) * 32 + 6) / 7;
            float s = 0.f;
            for (int x = xs; x < xe; ++x) s += bf2f(rowp[(size_t)x * QKV_N]);
            acc[PX] += s;
        }
    }
    int rcnt = ye - ys;
#pragma unroll
    for (int PX = 0; PX < 7; ++PX) {
        const int xs = PX * 32 / 7, xe = ((PX + 1) * 32 + 6) / 7;
        agents[((size_t)(b * AGENTS + py * 7 + PX)) * CH + ch] =
            acc[PX] / (float)(rcnt * (xe - xs));
    }
}

// ---------------- bilinear 7x7 sample (half-pixel, clamped) ----------------
__device__ inline float bilin7(const float* __restrict__ m, float sy, float sx) {
    float fy0 = floorf(sy), fx0 = floorf(sx);
    int y0 = (int)fy0, x0 = (int)fx0;
    float fy = sy - fy0, fx = sx - fx0;
    int y0c = min(max(y0, 0), 6), y1c = min(max(y0 + 1, 0), 6);
    int x0c = min(max(x0, 0), 6), x1c = min(max(x0 + 1, 0), 6);
    float v00 = m[y0c * 7 + x0c], v01 = m[y0c * 7 + x1c];
    float v10 = m[y1c * 7 + x0c], v11 = m[y1c * 7 + x1c];
    return (1.f - fy) * ((1.f - fx) * v00 + fx * v01) + fy * ((1.f - fx) * v10 + fx * v11);
}

// pbn[h][n][64] = resize(an_bias)[h,a,y,x] + ah_bias[h,a,y] + aw_bias[h,a,x]  (n-major, a rows 49..63 zero)
__global__ void pb_kernel(const float* __restrict__ an, const float* __restrict__ ahb,
                          const float* __restrict__ awb, float* __restrict__ pbn) {
    int h = blockIdx.x >> 6, a = blockIdx.x & 63;
    if (a >= AGENTS) {
        for (int n = threadIdx.x; n < NTOK; n += 256)
            pbn[((size_t)(h * NTOK + n)) * 64 + a] = 0.f;
        return;
    }
    const float* m = an + (h * AGENTS + a) * 49;
    for (int n = threadIdx.x; n < NTOK; n += 256) {
        int y = n >> 5, x = n & 31;
        float v = bilin7(m, (y + 0.5f) * (7.f / 32.f) - 0.5f, (x + 0.5f) * (7.f / 32.f) - 0.5f);
        v += ahb[(h * AGENTS + a) * 32 + y] + awb[(h * AGENTS + a) * 32 + x];
        pbn[((size_t)(h * NTOK + n)) * 64 + a] = v;
    }
}

// abT[h][a][n] = resize(na_bias)[h,a,y,x] + ha_bias[h,y,a] + wa_bias[h,x,a]   (a-major)
__global__ void ab_kernel(const float* __restrict__ na, const float* __restrict__ hab,
                          const float* __restrict__ wab, float* __restrict__ abT) {
    int idx = blockIdx.x * 256 + threadIdx.x;          // = (h*49 + a)*1024 + n
    if (idx >= HEADS * AGENTS * NTOK) return;
    int h = idx / (AGENTS * NTOK);
    int r = idx % (AGENTS * NTOK);
    int a = r / NTOK, n = r % NTOK;
    int y = n >> 5, x = n & 31;
    const float* m = na + (h * AGENTS + a) * 49;
    float v = bilin7(m, (y + 0.5f) * (7.f / 32.f) - 0.5f, (x + 0.5f) * (7.f / 32.f) - 0.5f);
    v += hab[(h * 32 + y) * AGENTS + a] + wab[(h * 32 + x) * AGENTS + a];
    abT[idx] = v;
}

// ============ fused attention: agent-attn (MFMA) + q-attn (MFMA) + dwc ============
// grid = 256 (b,h); 512 threads = 8 waves. Phase 1 = agent attention -> avT in LDS.
// Phase 2 = q attention + depthwise conv; V taps and PV B-operand both from the Vt transpose.
#define VTP 1038   // V^T row pad: 519 dw, %32=7 -> fr rows on distinct banks
__global__ __launch_bounds__(512) void fused_attn(const u16* __restrict__ qkvb,
                                                  const float* __restrict__ agents,
                                                  const float* __restrict__ pbn,
                                                  const float* __restrict__ abT,
                                                  const float* __restrict__ dwc_w,
                                                  const float* __restrict__ dwc_b,
                                                  u16* __restrict__ outbf) {
    int b = blockIdx.x >> 3, h = blockIdx.x & 7;
    int tid = threadIdx.x, lane = tid & 63, w = tid >> 6;
    const int fr = lane & 15, fq = lane >> 4;

    __shared__ u16 ah_lds[64 * 32];       // 4 KB, scale folded, rows 49..63 zero
    __shared__ u16 Vt[32 * VTP];          // 66.4 KB  V^T [dim][token] (both phases)
    __shared__ float PO[8][2304];         // 73.7 KB  per-wave P/O scratch
    __shared__ float lsum_lds[8][64];     // 2 KB
    __shared__ u16 avT[32][72];           // 4.6 KB  agent_v^T bf16 (phase 2)
    __shared__ float w9[9][32];           // 1.15 KB
    __shared__ float bia[32];

    u16*   Pw = (u16*)&PO[w][0];
    float* Ow = &PO[w][0];

    // ---- staging (cooperative) ----
    for (int li = tid; li < 64 * 32; li += 512) {
        int a = li >> 5, d = li & 31;
        float v = (a < AGENTS) ? agents[((size_t)(b * AGENTS + a)) * CH + h * HD + d] * SCALE : 0.f;
        ah_lds[li] = f2bf1(v);
    }
    // V^T staging: token-pair repack -> u16x2 writes (<=2-way banked, half the insts)
    for (int li = tid; li < 512 * 4; li += 512) {
        int p = li >> 2, d8 = (li & 3) * 8;       // tokens 2p,2p+1 ; dims d8..d8+7
        const u16* g0 = &qkvb[((size_t)(b * NTOK + 2 * p)) * QKV_N + 2 * CH + h * HD + d8];
        u16x8 va = *(const u16x8*)g0;
        u16x8 vb = *(const u16x8*)(g0 + QKV_N);
#pragma unroll
        for (int j = 0; j < 8; ++j) {
            u16x2 w2; w2[0] = va[j]; w2[1] = vb[j];
            *(u16x2*)&Vt[(d8 + j) * VTP + 2 * p] = w2;
        }
    }
    for (int li = tid; li < 288; li += 512) {
        int t = li >> 5, d = li & 31;
        w9[t][d] = dwc_w[(h * HD + d) * 9 + t];
    }
    if (tid < 32) bia[tid] = dwc_b[h * HD + tid];
    __syncthreads();

    // ================= phase 1: agent attention =================
    short8 ahf[4];
#pragma unroll
    for (int mt = 0; mt < 4; ++mt)
        ahf[mt] = *(const short8*)&ah_lds[(mt * 16 + fr) * 32 + fq * 8];

    float lsum[4][4];
#pragma unroll
    for (int mt = 0; mt < 4; ++mt)
#pragma unroll
        for (int j = 0; j < 4; ++j) lsum[mt][j] = 0.f;
    f32x4 accA[4][2];
#pragma unroll
    for (int mt = 0; mt < 4; ++mt)
#pragma unroll
        for (int ntd = 0; ntd < 2; ++ntd) accA[mt][ntd] = (f32x4)(0.f);

    const float* pbnh = pbn + (size_t)h * NTOK * 64;

#pragma unroll
    for (int c2 = 0; c2 < 2; ++c2) {
        int tb = w * 128 + c2 * 64;
        short8 kf[4];
#pragma unroll
        for (int nt = 0; nt < 4; ++nt)
            kf[nt] = *(const short8*)&qkvb[((size_t)(b * NTOK + tb + nt * 16 + fr)) * QKV_N + CH + h * HD + fq * 8];

#pragma unroll
        for (int mt = 0; mt < 4; ++mt) {
            f32x4 accS[4], pbq[4];
#pragma unroll
            for (int nt = 0; nt < 4; ++nt) {
                accS[nt] = __builtin_amdgcn_mfma_f32_16x16x32_bf16(ahf[mt], kf[nt], (f32x4)(0.f), 0, 0, 0);
                pbq[nt] = *(const f32x4*)&pbnh[(size_t)(tb + nt * 16 + fr) * 64 + mt * 16 + fq * 4];
            }
#pragma unroll
            for (int j = 0; j < 4; ++j) {
                int a = mt * 16 + fq * 4 + j;
#pragma unroll
                for (int nt = 0; nt < 4; ++nt) {
                    float e = __expf(accS[nt][j] + pbq[nt][j]);
                    lsum[mt][j] += e;
                    Pw[a * 72 + nt * 16 + fr] = f2bf1(e);
                }
            }
        }

        asm volatile("s_waitcnt lgkmcnt(0)" ::: "memory");
        __builtin_amdgcn_sched_barrier(0);

        short8 pf[4][2], vf[2][2];
#pragma unroll
        for (int mt = 0; mt < 4; ++mt)
#pragma unroll
            for (int kc = 0; kc < 2; ++kc)
                pf[mt][kc] = *(const short8*)&Pw[(mt * 16 + fr) * 72 + kc * 32 + fq * 8];
#pragma unroll
        for (int ntd = 0; ntd < 2; ++ntd)
#pragma unroll
            for (int kc = 0; kc < 2; ++kc)
                vf[ntd][kc] = *(const short8*)&Vt[(ntd * 16 + fr) * VTP + tb + kc * 32 + fq * 8];

        asm volatile("s_waitcnt lgkmcnt(0)" ::: "memory");
        __builtin_amdgcn_sched_barrier(0);

#pragma unroll
        for (int mt = 0; mt < 4; ++mt)
#pragma unroll
            for (int kc = 0; kc < 2; ++kc)
#pragma unroll
                for (int ntd = 0; ntd < 2; ++ntd)
                    accA[mt][ntd] = __builtin_amdgcn_mfma_f32_16x16x32_bf16(pf[mt][kc], vf[ntd][kc], accA[mt][ntd], 0, 0, 0);
    }

#pragma unroll
    for (int mt = 0; mt < 4; ++mt)
#pragma unroll
        for (int j = 0; j < 4; ++j) {
            float s = lsum[mt][j];
            s += __shfl_xor(s, 1);
            s += __shfl_xor(s, 2);
            s += __shfl_xor(s, 4);
            s += __shfl_xor(s, 8);
            lsum[mt][j] = s;
        }
    if (fr == 0) {
#pragma unroll
        for (int mt = 0; mt < 4; ++mt)
#pragma unroll
            for (int j = 0; j < 4; ++j)
                lsum_lds[w][mt * 16 + fq * 4 + j] = lsum[mt][j];
    }

#pragma unroll
    for (int mt = 0; mt < 4; ++mt)
#pragma unroll
        for (int ntd = 0; ntd < 2; ++ntd)
#pragma unroll
            for (int j = 0; j < 4; ++j)
                Ow[(mt * 16 + fq * 4 + j) * 32 + ntd * 16 + fr] = accA[mt][ntd][j];

    asm volatile("s_waitcnt lgkmcnt(0)" ::: "memory");
    __syncthreads();

    // merge 8 waves -> avT (bf16, [d][a], rows a>=49 zero)
    for (int li = tid; li < 64 * HD; li += 512) {
        int a = li & 63, d = li >> 6;
        float val = 0.f;
        if (a < AGENTS) {
            float L = 0.f, o = 0.f;
#pragma unroll
            for (int ww = 0; ww < 8; ++ww) {
                o += PO[ww][a * 32 + d];
                L += lsum_lds[ww][a];
            }
            val = o / L;
        }
        avT[d][a] = f2bf1(val);
    }
    __syncthreads();

    // ================= phase 2: q attention + dwc =================
    short8 avf[2][2];
#pragma unroll
    for (int ntd = 0; ntd < 2; ++ntd)
#pragma unroll
        for (int kc = 0; kc < 2; ++kc)
            avf[ntd][kc] = *(const short8*)&avT[ntd * 16 + fr][kc * 32 + fq * 8];

    const float* abTh = abT + (size_t)h * AGENTS * NTOK;

#pragma unroll
    for (int hh = 0; hh < 4; ++hh) {
        int hb = w * 128 + hh * 32;

        // S = Q @ ah^T, softmax, P -> LDS (32-token chunk, pad 68)
#pragma unroll
        for (int mt2 = 0; mt2 < 2; ++mt2) {
            int tok = hb + mt2 * 16 + fr;
            short8 qf = *(const short8*)(qkvb + ((size_t)(b * NTOK + tok)) * QKV_N + h * HD + fq * 8);
            f32x4 accS[4];
            f32x4 abv[4];
#pragma unroll
            for (int nt = 0; nt < 4; ++nt) {
                accS[nt] = __builtin_amdgcn_mfma_f32_16x16x32_bf16(qf, ahf[nt], (f32x4)(0.f), 0, 0, 0);
                abv[nt] = *(const f32x4*)&abTh[(size_t)min(nt * 16 + fr, AGENTS - 1) * NTOK + hb + mt2 * 16 + fq * 4];
            }

            float e[4][4];   // [j][nt]
            float ps[4];
#pragma unroll
            for (int j = 0; j < 4; ++j) ps[j] = 0.f;
#pragma unroll
            for (int j = 0; j < 4; ++j) {
#pragma unroll
                for (int nt = 0; nt < 4; ++nt) {
                    int a = nt * 16 + fr;
                    float s = accS[nt][j] + abv[nt][j];
                    float ev = (a < AGENTS) ? __expf(s) : 0.f;
                    e[j][nt] = ev;
                    ps[j] += ev;
                }
            }
#pragma unroll
            for (int j = 0; j < 4; ++j) {
                ps[j] += __shfl_xor(ps[j], 1);
                ps[j] += __shfl_xor(ps[j], 2);
                ps[j] += __shfl_xor(ps[j], 4);
                ps[j] += __shfl_xor(ps[j], 8);
            }
#pragma unroll
            for (int j = 0; j < 4; ++j) {
                float inv = 1.f / ps[j];
                int tl = mt2 * 16 + fq * 4 + j;
#pragma unroll
                for (int nt = 0; nt < 4; ++nt)
                    Pw[tl * 68 + nt * 16 + fr] = f2bf1(e[j][nt] * inv);
            }
        }

        asm volatile("s_waitcnt lgkmcnt(0)" ::: "memory");
        __builtin_amdgcn_sched_barrier(0);

        short8 pf2[2][2];
#pragma unroll
        for (int mt2 = 0; mt2 < 2; ++mt2)
#pragma unroll
            for (int kc = 0; kc < 2; ++kc)
                pf2[mt2][kc] = *(const short8*)&Pw[(mt2 * 16 + fr) * 68 + kc * 32 + fq * 8];

        asm volatile("s_waitcnt lgkmcnt(0)" ::: "memory");
        __builtin_amdgcn_sched_barrier(0);

        f32x4 accO[2][2];
#pragma unroll
        for (int mt2 = 0; mt2 < 2; ++mt2)
#pragma unroll
            for (int ntd = 0; ntd < 2; ++ntd) accO[mt2][ntd] = (f32x4)(0.f);
#pragma unroll
        for (int mt2 = 0; mt2 < 2; ++mt2)
#pragma unroll
            for (int kc = 0; kc < 2; ++kc)
#pragma unroll
                for (int ntd = 0; ntd < 2; ++ntd)
                    accO[mt2][ntd] = __builtin_amdgcn_mfma_f32_16x16x32_bf16(pf2[mt2][kc], avf[ntd][kc], accO[mt2][ntd], 0, 0, 0);

        // fused dwc + bias + bf16 store (C-layout epilogue); V taps via u16x2 spans
        int y = w * 4 + hh;
#pragma unroll
        for (int ntd = 0; ntd < 2; ++ntd) {
            int d = ntd * 16 + fr;
            float wv[9];
#pragma unroll
            for (int t = 0; t < 9; ++t) wv[t] = w9[t][d];
            float bv = bia[d];
            const u16* Vd = &Vt[d * VTP];
#pragma unroll
            for (int mt2 = 0; mt2 < 2; ++mt2) {
                int x0 = mt2 * 16 + fq * 4;
                float sp[3][8];      // tokens x0-2 .. x0+5 per dy row
#pragma unroll
                for (int dy = 0; dy < 3; ++dy) {
                    int yy = y - 1 + dy;
                    if (yy >= 0 && yy < 32) {
                        int base = yy * 32 + x0 - 2;     // even -> 4B-aligned
                        u16x2 r0 = *(const u16x2*)&Vd[base];
                        u16x2 r1 = *(const u16x2*)&Vd[base + 2];
                        u16x2 r2 = *(const u16x2*)&Vd[base + 4];
                        u16x2 r3 = *(const u16x2*)&Vd[base + 6];
                        sp[dy][0] = bf2f(r0[0]); sp[dy][1] = bf2f(r0[1]);
                        sp[dy][2] = bf2f(r1[0]); sp[dy][3] = bf2f(r1[1]);
                        sp[dy][4] = bf2f(r2[0]); sp[dy][5] = bf2f(r2[1]);
                        sp[dy][6] = bf2f(r3[0]); sp[dy][7] = bf2f(r3[1]);
                    } else {
#pragma unroll
                        for (int k = 0; k < 8; ++k) sp[dy][k] = 0.f;
                    }
                }
                float vv[3][6];      // xx = x0-1+k, masked at image edges
#pragma unroll
                for (int dy = 0; dy < 3; ++dy)
#pragma unroll
                    for (int k = 0; k < 6; ++k) {
                        int xx = x0 - 1 + k;
                        vv[dy][k] = (xx >= 0 && xx < 32) ? sp[dy][k + 1] : 0.f;
                    }
#pragma unroll
                for (int j = 0; j < 4; ++j) {
                    float o = accO[mt2][ntd][j] + bv;
#pragma unroll
                    for (int dy = 0; dy < 3; ++dy)
#pragma unroll
                        for (int dx = 0; dx < 3; ++dx)
                            o = fmaf(wv[dy * 3 + dx], vv[dy][j + dx], o);
                    int n = y * 32 + x0 + j;
                    outbf[((size_t)(b * 1025 + 1 + n)) * CH + h * HD + d] = f2bf1(o);
                }
            }
        }
    }
}
#undef VTP

extern "C" void kernel_launch(void* const* d_in, const int* in_sizes, int n_in,
                              void* d_out, int out_size, void* d_ws, size_t ws_size,
                              hipStream_t stream) {
    const float* x      = (const float*)d_in[0];
    const float* qkv_w  = (const float*)d_in[1];
    const float* proj_w = (const float*)d_in[2];
    const float* proj_b = (const float*)d_in[3];
    const float* dwc_w  = (const float*)d_in[4];
    const float* dwc_b  = (const float*)d_in[5];
    const float* an_b   = (const float*)d_in[6];
    const float* ah_b   = (const float*)d_in[7];
    const float* aw_b   = (const float*)d_in[8];
    const float* na_b   = (const float*)d_in[9];
    const float* ha_b   = (const float*)d_in[10];
    const float* wa_b   = (const float*)d_in[11];
    float* out = (float*)d_out;

    float* ws      = (float*)d_ws;
    u16*   qkvb    = (u16*)ws;                 // 25,165,824 u16 (bf16 qkv)
    float* agents  = ws + 12582912;            // 401,408 f
    float* pbn     = agents + 401408;          // 524,288 f  (n-major [h][n][64])
    float* abT     = pbn + 524288;             // 401,408 f  (a-major [h][a][n])
    u16* xbf  = (u16*)(abT + 401408);          // 8,396,800 u16 (x bf16 -> fused bf16 rows)
    u16* qwbf = xbf + 8396800;                 // 196,608 u16
    u16* pwbf = qwbf + 196608;                 // 65,536 u16

    // conversions (xbf rows b*1025 keep bf16 cls tokens for the proj GEMM)
    f2bf_kernel<<<4100, 256, 0, stream>>>(x, xbf, 8396800 / 8);
    f2bf_kernel<<<96, 256, 0, stream>>>(qkv_w, qwbf, 196608 / 8);
    f2bf_kernel<<<32, 256, 0, stream>>>(proj_w, pwbf, 65536 / 8);
    // 1. qkv(bf16) = xs @ qkv_w^T   (M=32768, N=768, K=256)
    gemm_bf16<<<dim3(256, 6), 256, 0, stream>>>(xbf, qwbf, nullptr, qkvb, 32768, 768, 256, nullptr, 1);
    // 2. agent pooling of q
    pool_kernel<<<BATCH * 7, 256, 0, stream>>>(qkvb, agents);
    // 3. position biases (pbn n-major with zero pad rows; abT a-major)
    pb_kernel<<<HEADS * 64, 256, 0, stream>>>(an_b, ah_b, aw_b, pbn);
    ab_kernel<<<(HEADS * AGENTS * NTOK + 255) / 256, 256, 0, stream>>>(na_b, ha_b, wa_b, abT);
    // 4. fused agent-attn + q-attn + dwc -> bf16 rows 1..1024 of xbf
    fused_attn<<<BATCH * HEADS, 512, 0, stream>>>(qkvb, agents, pbn, abT, dwc_w, dwc_b, xbf);
    // 5. out = fused @ proj_w^T + proj_b  (M=32800, N=256, K=256)
    gemm_bf16<<<dim3(257, 2), 256, 0, stream>>>(xbf, pwbf, out, nullptr, 32800, 256, 256, proj_b, 0);
}

// Round 11
// 133.848 us; speedup vs baseline: 1.0932x; 1.0030x over previous
//
#include <hip/hip_runtime.h>
#include <hip/hip_bf16.h>

// Problem constants
#define BATCH 32
#define NTOK 1024          // 32x32
#define CH 256
#define HEADS 8
#define HD 32
#define AGENTS 49
#define WIN 32
#define QKV_N 768
#define SCALE 0.17677669529663687f   // 1/sqrt(32)

typedef unsigned short u16;
typedef __attribute__((ext_vector_type(2))) unsigned short u16x2;
typedef __attribute__((ext_vector_type(8))) unsigned short u16x8;
typedef __attribute__((ext_vector_type(8))) short short8;
typedef __attribute__((ext_vector_type(4))) float f32x4;

__device__ __forceinline__ void gload_lds16(const void* g, const void* l) {
    __builtin_amdgcn_global_load_lds(
        (const __attribute__((address_space(1))) unsigned int*)g,
        (__attribute__((address_space(3))) unsigned int*)l, 16, 0, 0);
}

__device__ __forceinline__ u16 f2bf1(float f) {
    unsigned u = __builtin_bit_cast(unsigned, f);
    u += 0x7fffu + ((u >> 16) & 1u);
    return (u16)(u >> 16);
}
__device__ __forceinline__ float bf2f(u16 v) {
    unsigned u = ((unsigned)v) << 16;
    return __builtin_bit_cast(float, u);
}

// ---------------- fp32 -> bf16 conversion, 8 elems/thread ----------------
__global__ void f2bf_kernel(const float* __restrict__ in, u16* __restrict__ out, int n8) {
    int i = blockIdx.x * 256 + threadIdx.x;
    if (i >= n8) return;
    float4 v0 = ((const float4*)in)[i * 2];
    float4 v1 = ((const float4*)in)[i * 2 + 1];
    u16x8 o;
    o[0] = f2bf1(v0.x); o[1] = f2bf1(v0.y); o[2] = f2bf1(v0.z); o[3] = f2bf1(v0.w);
    o[4] = f2bf1(v1.x); o[5] = f2bf1(v1.y); o[6] = f2bf1(v1.z); o[7] = f2bf1(v1.w);
    ((u16x8*)out)[i] = o;
}

// ---------------- bf16 MFMA GEMM: C[M,N] = A[M,K] @ B[N,K]^T (+bias) ----------------
__global__ __launch_bounds__(256) void gemm_bf16(const u16* __restrict__ A,
                                                 const u16* __restrict__ B,
                                                 float* __restrict__ C,
                                                 u16* __restrict__ C16,
                                                 int M, int N, int K,
                                                 const float* __restrict__ bias,
                                                 int amode) {
    __shared__ u16 As[128 * 32];
    __shared__ u16 Bs[128 * 32];
    const int tid = threadIdx.x;
    const int lane = tid & 63;
    const int wid = tid >> 6;
    const int row0 = blockIdx.x * 128, col0 = blockIdx.y * 128;
    const int wr = wid >> 1, wc = wid & 1;
    const int fr = lane & 15, fq = lane >> 4;

    f32x4 acc[4][4];
#pragma unroll
    for (int m = 0; m < 4; ++m)
#pragma unroll
        for (int n = 0; n < 4; ++n) acc[m][n] = (f32x4)(0.f);

    for (int k0 = 0; k0 < K; k0 += 32) {
#pragma unroll
        for (int r = 0; r < 2; ++r) {
            int trow = (tid >> 2) + r * 64;
            int tcol = (tid & 3) * 8;
            size_t aoff;
            int grow = row0 + trow;
            if (amode == 1) {
                int bb = grow >> 10, nn = grow & 1023;
                aoff = ((size_t)(bb * 1025 + nn + 1)) * 256 + (size_t)(k0 + tcol);
            } else {
                if (grow >= M) grow = M - 1;
                aoff = (size_t)grow * K + (size_t)(k0 + tcol);
            }
            gload_lds16(A + aoff, (const char*)As + wid * 1024 + r * 4096);
            int brow = col0 + trow;
            gload_lds16(B + (size_t)brow * K + (size_t)(k0 + tcol),
                        (const char*)Bs + wid * 1024 + r * 4096);
        }
        __syncthreads();

        short8 af[4], bf[4];
#pragma unroll
        for (int m = 0; m < 4; ++m)
            af[m] = *(const short8*)&As[(wr * 64 + m * 16 + fr) * 32 + fq * 8];
#pragma unroll
        for (int n = 0; n < 4; ++n)
            bf[n] = *(const short8*)&Bs[(wc * 64 + n * 16 + fr) * 32 + fq * 8];
#pragma unroll
        for (int m = 0; m < 4; ++m)
#pragma unroll
            for (int n = 0; n < 4; ++n)
                acc[m][n] = __builtin_amdgcn_mfma_f32_16x16x32_bf16(af[m], bf[n], acc[m][n], 0, 0, 0);
        __syncthreads();
    }

#pragma unroll
    for (int m = 0; m < 4; ++m) {
#pragma unroll
        for (int j = 0; j < 4; ++j) {
            int row = row0 + wr * 64 + m * 16 + fq * 4 + j;
            if (row < M) {
#pragma unroll
                for (int n = 0; n < 4; ++n) {
                    int col = col0 + wc * 64 + n * 16 + fr;
                    float v = acc[m][n][j];
                    if (bias) v += bias[col];
                    if (C16) C16[(size_t)row * N + col] = f2bf1(v);
                    else     C[(size_t)row * N + col] = v;
                }
            }
        }
    }
}

// ------- adaptive avg pool of q (bf16) -> agents (b,49,256) f32 -------
__global__ __launch_bounds__(256) void pool_kernel(const u16* __restrict__ qkvb,
                                                   float* __restrict__ agents) {
    int b = blockIdx.x / 7, py = blockIdx.x % 7;
    int ch = threadIdx.x;
    int ys = py * 32 / 7, ye = ((py + 1) * 32 + 6) / 7;
    float acc[7];
#pragma unroll
    for (int i = 0; i < 7; ++i) acc[i] = 0.f;
    for (int y = ys; y < ye; ++y) {
        const u16* rowp = qkvb + ((size_t)(b * NTOK + y * 32)) * QKV_N + ch;
#pragma unroll
        for (int PX = 0; PX < 7; ++PX) {
            const int xs = PX * 32 / 7, xe = ((PX + 1) * 32 + 6) / 7;
            float s = 0.f;
            for (int x = xs; x < xe; ++x) s += bf2f(rowp[(size_t)x * QKV_N]);
            acc[PX] += s;
        }
    }
    int rcnt = ye - ys;
#pragma unroll
    for (int PX = 0; PX < 7; ++PX) {
        const int xs = PX * 32 / 7, xe = ((PX + 1) * 32 + 6) / 7;
        agents[((size_t)(b * AGENTS + py * 7 + PX)) * CH + ch] =
            acc[PX] / (float)(rcnt * (xe - xs));
    }
}

// ---------------- bilinear 7x7 sample (half-pixel, clamped) ----------------
__device__ inline float bilin7(const float* __restrict__ m, float sy, float sx) {
    float fy0 = floorf(sy), fx0 = floorf(sx);
    int y0 = (int)fy0, x0 = (int)fx0;
    float fy = sy - fy0, fx = sx - fx0;
    int y0c = min(max(y0, 0), 6), y1c = min(max(y0 + 1, 0), 6);
    int x0c = min(max(x0, 0), 6), x1c = min(max(x0 + 1, 0), 6);
    float v00 = m[y0c * 7 + x0c], v01 = m[y0c * 7 + x1c];
    float v10 = m[y1c * 7 + x0c], v11 = m[y1c * 7 + x1c];
    return (1.f - fy) * ((1.f - fx) * v00 + fx * v01) + fy * ((1.f - fx) * v10 + fx * v11);
}

// pbn[h][n][64] = resize(an_bias)[h,a,y,x] + ah_bias[h,a,y] + aw_bias[h,a,x]  (n-major, a rows 49..63 zero)
__global__ void pb_kernel(const float* __restrict__ an, const float* __restrict__ ahb,
                          const float* __restrict__ awb, float* __restrict__ pbn) {
    int h = blockIdx.x >> 6, a = blockIdx.x & 63;
    if (a >= AGENTS) {
        for (int n = threadIdx.x; n < NTOK; n += 256)
            pbn[((size_t)(h * NTOK + n)) * 64 + a] = 0.f;
        return;
    }
    const float* m = an + (h * AGENTS + a) * 49;
    for (int n = threadIdx.x; n < NTOK; n += 256) {
        int y = n >> 5, x = n & 31;
        float v = bilin7(m, (y + 0.5f) * (7.f / 32.f) - 0.5f, (x + 0.5f) * (7.f / 32.f) - 0.5f);
        v += ahb[(h * AGENTS + a) * 32 + y] + awb[(h * AGENTS + a) * 32 + x];
        pbn[((size_t)(h * NTOK + n)) * 64 + a] = v;
    }
}

// abT[h][a][n] = resize(na_bias)[h,a,y,x] + ha_bias[h,y,a] + wa_bias[h,x,a]   (a-major)
__global__ void ab_kernel(const float* __restrict__ na, const float* __restrict__ hab,
                          const float* __restrict__ wab, float* __restrict__ abT) {
    int idx = blockIdx.x * 256 + threadIdx.x;          // = (h*49 + a)*1024 + n
    if (idx >= HEADS * AGENTS * NTOK) return;
    int h = idx / (AGENTS * NTOK);
    int r = idx % (AGENTS * NTOK);
    int a = r / NTOK, n = r % NTOK;
    int y = n >> 5, x = n & 31;
    const float* m = na + (h * AGENTS + a) * 49;
    float v = bilin7(m, (y + 0.5f) * (7.f / 32.f) - 0.5f, (x + 0.5f) * (7.f / 32.f) - 0.5f);
    v += hab[(h * 32 + y) * AGENTS + a] + wab[(h * 32 + x) * AGENTS + a];
    abT[idx] = v;
}

// ============ fused attention: agent-attn (MFMA) + q-attn (MFMA) + dwc ============
// grid = 256 (b,h); 512 threads = 8 waves. Phase 1 = agent attention -> avT in LDS.
// Phase 2 = q attention + depthwise conv; V taps and PV B-operand both from the Vt transpose.
// NOTE: no manual lgkmcnt fences inside the phases — all P-buffer traffic is same-wave,
// same-type LDS; the compiler orders aliasing LDS ops and emits counted lgkmcnt (m97).
// The single kept fence guards the type-punned float O-writeback over the u16 P region (TBAA).
#define VTP 1038   // V^T row pad: 519 dw, %32=7 -> fr rows on distinct banks
__global__ __launch_bounds__(512) void fused_attn(const u16* __restrict__ qkvb,
                                                  const float* __restrict__ agents,
                                                  const float* __restrict__ pbn,
                                                  const float* __restrict__ abT,
                                                  const float* __restrict__ dwc_w,
                                                  const float* __restrict__ dwc_b,
                                                  u16* __restrict__ outbf) {
    int b = blockIdx.x >> 3, h = blockIdx.x & 7;
    int tid = threadIdx.x, lane = tid & 63, w = tid >> 6;
    const int fr = lane & 15, fq = lane >> 4;

    __shared__ u16 ah_lds[64 * 32];       // 4 KB, scale folded, rows 49..63 zero
    __shared__ u16 Vt[32 * VTP];          // 66.4 KB  V^T [dim][token] (both phases)
    __shared__ float PO[8][2304];         // 73.7 KB  per-wave P/O scratch
    __shared__ float lsum_lds[8][64];     // 2 KB
    __shared__ u16 avT[32][72];           // 4.6 KB  agent_v^T bf16 (phase 2)
    __shared__ float w9[9][32];           // 1.15 KB
    __shared__ float bia[32];

    u16*   Pw = (u16*)&PO[w][0];
    float* Ow = &PO[w][0];

    // ---- staging (cooperative) ----
    for (int li = tid; li < 64 * 32; li += 512) {
        int a = li >> 5, d = li & 31;
        float v = (a < AGENTS) ? agents[((size_t)(b * AGENTS + a)) * CH + h * HD + d] * SCALE : 0.f;
        ah_lds[li] = f2bf1(v);
    }
    // V^T staging: token-pair repack -> u16x2 writes (<=2-way banked)
    for (int li = tid; li < 512 * 4; li += 512) {
        int p = li >> 2, d8 = (li & 3) * 8;       // tokens 2p,2p+1 ; dims d8..d8+7
        const u16* g0 = &qkvb[((size_t)(b * NTOK + 2 * p)) * QKV_N + 2 * CH + h * HD + d8];
        u16x8 va = *(const u16x8*)g0;
        u16x8 vb = *(const u16x8*)(g0 + QKV_N);
#pragma unroll
        for (int j = 0; j < 8; ++j) {
            u16x2 w2; w2[0] = va[j]; w2[1] = vb[j];
            *(u16x2*)&Vt[(d8 + j) * VTP + 2 * p] = w2;
        }
    }
    for (int li = tid; li < 288; li += 512) {
        int t = li >> 5, d = li & 31;
        w9[t][d] = dwc_w[(h * HD + d) * 9 + t];
    }
    if (tid < 32) bia[tid] = dwc_b[h * HD + tid];
    __syncthreads();

    // ================= phase 1: agent attention =================
    short8 ahf[4];
#pragma unroll
    for (int mt = 0; mt < 4; ++mt)
        ahf[mt] = *(const short8*)&ah_lds[(mt * 16 + fr) * 32 + fq * 8];

    // preload K fragments for BOTH chunks (hide global latency under chunk-0 compute)
    short8 kf[2][4];
#pragma unroll
    for (int c2 = 0; c2 < 2; ++c2)
#pragma unroll
        for (int nt = 0; nt < 4; ++nt)
            kf[c2][nt] = *(const short8*)&qkvb[((size_t)(b * NTOK + w * 128 + c2 * 64 + nt * 16 + fr)) * QKV_N + CH + h * HD + fq * 8];

    float lsum[4][4];
#pragma unroll
    for (int mt = 0; mt < 4; ++mt)
#pragma unroll
        for (int j = 0; j < 4; ++j) lsum[mt][j] = 0.f;
    f32x4 accA[4][2];
#pragma unroll
    for (int mt = 0; mt < 4; ++mt)
#pragma unroll
        for (int ntd = 0; ntd < 2; ++ntd) accA[mt][ntd] = (f32x4)(0.f);

    const float* pbnh = pbn + (size_t)h * NTOK * 64;

#pragma unroll
    for (int c2 = 0; c2 < 2; ++c2) {
        int tb = w * 128 + c2 * 64;

        // pb bias: one-mt lookahead double buffer
        f32x4 pbq[2][4];
#pragma unroll
        for (int nt = 0; nt < 4; ++nt)
            pbq[0][nt] = *(const f32x4*)&pbnh[(size_t)(tb + nt * 16 + fr) * 64 + fq * 4];

#pragma unroll
        for (int mt = 0; mt < 4; ++mt) {
            f32x4 accS[4];
#pragma unroll
            for (int nt = 0; nt < 4; ++nt)
                accS[nt] = __builtin_amdgcn_mfma_f32_16x16x32_bf16(ahf[mt], kf[c2][nt], (f32x4)(0.f), 0, 0, 0);
            if (mt < 3) {
#pragma unroll
                for (int nt = 0; nt < 4; ++nt)
                    pbq[(mt + 1) & 1][nt] = *(const f32x4*)&pbnh[(size_t)(tb + nt * 16 + fr) * 64 + (mt + 1) * 16 + fq * 4];
            }
#pragma unroll
            for (int j = 0; j < 4; ++j) {
                int a = mt * 16 + fq * 4 + j;
#pragma unroll
                for (int nt = 0; nt < 4; ++nt) {
                    float e = __expf(accS[nt][j] + pbq[mt & 1][nt][j]);
                    lsum[mt][j] += e;
                    Pw[a * 72 + nt * 16 + fr] = f2bf1(e);
                }
            }
        }

        short8 pf[4][2], vf[2][2];
#pragma unroll
        for (int mt = 0; mt < 4; ++mt)
#pragma unroll
            for (int kc = 0; kc < 2; ++kc)
                pf[mt][kc] = *(const short8*)&Pw[(mt * 16 + fr) * 72 + kc * 32 + fq * 8];
#pragma unroll
        for (int ntd = 0; ntd < 2; ++ntd)
#pragma unroll
            for (int kc = 0; kc < 2; ++kc)
                vf[ntd][kc] = *(const short8*)&Vt[(ntd * 16 + fr) * VTP + tb + kc * 32 + fq * 8];

#pragma unroll
        for (int mt = 0; mt < 4; ++mt)
#pragma unroll
            for (int kc = 0; kc < 2; ++kc)
#pragma unroll
                for (int ntd = 0; ntd < 2; ++ntd)
                    accA[mt][ntd] = __builtin_amdgcn_mfma_f32_16x16x32_bf16(pf[mt][kc], vf[ntd][kc], accA[mt][ntd], 0, 0, 0);
    }

#pragma unroll
    for (int mt = 0; mt < 4; ++mt)
#pragma unroll
        for (int j = 0; j < 4; ++j) {
            float s = lsum[mt][j];
            s += __shfl_xor(s, 1);
            s += __shfl_xor(s, 2);
            s += __shfl_xor(s, 4);
            s += __shfl_xor(s, 8);
            lsum[mt][j] = s;
        }
    if (fr == 0) {
#pragma unroll
        for (int mt = 0; mt < 4; ++mt)
#pragma unroll
            for (int j = 0; j < 4; ++j)
                lsum_lds[w][mt * 16 + fq * 4 + j] = lsum[mt][j];
    }

    // TBAA guard: float stores below alias the u16 P reads above (type-punned region)
    asm volatile("s_waitcnt lgkmcnt(0)" ::: "memory");
    __builtin_amdgcn_sched_barrier(0);

#pragma unroll
    for (int mt = 0; mt < 4; ++mt)
#pragma unroll
        for (int ntd = 0; ntd < 2; ++ntd)
#pragma unroll
            for (int j = 0; j < 4; ++j)
                Ow[(mt * 16 + fq * 4 + j) * 32 + ntd * 16 + fr] = accA[mt][ntd][j];

    __syncthreads();

    // merge 8 waves -> avT (bf16, [d][a], rows a>=49 zero)
    for (int li = tid; li < 64 * HD; li += 512) {
        int a = li & 63, d = li >> 6;
        float val = 0.f;
        if (a < AGENTS) {
            float L = 0.f, o = 0.f;
#pragma unroll
            for (int ww = 0; ww < 8; ++ww) {
                o += PO[ww][a * 32 + d];
                L += lsum_lds[ww][a];
            }
            val = o / L;
        }
        avT[d][a] = f2bf1(val);
    }
    __syncthreads();

    // ================= phase 2: q attention + dwc =================
    short8 avf[2][2];
#pragma unroll
    for (int ntd = 0; ntd < 2; ++ntd)
#pragma unroll
        for (int kc = 0; kc < 2; ++kc)
            avf[ntd][kc] = *(const short8*)&avT[ntd * 16 + fr][kc * 32 + fq * 8];

    // preload ALL Q fragments (hide global latency across the hh loop)
    short8 qf2[4][2];
#pragma unroll
    for (int hh = 0; hh < 4; ++hh)
#pragma unroll
        for (int mt2 = 0; mt2 < 2; ++mt2)
            qf2[hh][mt2] = *(const short8*)(qkvb + ((size_t)(b * NTOK + w * 128 + hh * 32 + mt2 * 16 + fr)) * QKV_N + h * HD + fq * 8);

    const float* abTh = abT + (size_t)h * AGENTS * NTOK;

#pragma unroll
    for (int hh = 0; hh < 4; ++hh) {
        int hb = w * 128 + hh * 32;

        // bias loads first (long latency), then S-MFMAs on preloaded Q frags
        f32x4 abv[2][4];
#pragma unroll
        for (int mt2 = 0; mt2 < 2; ++mt2)
#pragma unroll
            for (int nt = 0; nt < 4; ++nt)
                abv[mt2][nt] = *(const f32x4*)&abTh[(size_t)min(nt * 16 + fr, AGENTS - 1) * NTOK + hb + mt2 * 16 + fq * 4];

#pragma unroll
        for (int mt2 = 0; mt2 < 2; ++mt2) {
            f32x4 accS[4];
#pragma unroll
            for (int nt = 0; nt < 4; ++nt)
                accS[nt] = __builtin_amdgcn_mfma_f32_16x16x32_bf16(qf2[hh][mt2], ahf[nt], (f32x4)(0.f), 0, 0, 0);

            float e[4][4];   // [j][nt]
            float ps[4];
#pragma unroll
            for (int j = 0; j < 4; ++j) ps[j] = 0.f;
#pragma unroll
            for (int j = 0; j < 4; ++j) {
#pragma unroll
                for (int nt = 0; nt < 4; ++nt) {
                    int a = nt * 16 + fr;
                    float s = accS[nt][j] + abv[mt2][nt][j];
                    float ev = (a < AGENTS) ? __expf(s) : 0.f;
                    e[j][nt] = ev;
                    ps[j] += ev;
                }
            }
#pragma unroll
            for (int j = 0; j < 4; ++j) {
                ps[j] += __shfl_xor(ps[j], 1);
                ps[j] += __shfl_xor(ps[j], 2);
                ps[j] += __shfl_xor(ps[j], 4);
                ps[j] += __shfl_xor(ps[j], 8);
            }
#pragma unroll
            for (int j = 0; j < 4; ++j) {
                float inv = 1.f / ps[j];
                int tl = mt2 * 16 + fq * 4 + j;
#pragma unroll
                for (int nt = 0; nt < 4; ++nt)
                    Pw[tl * 68 + nt * 16 + fr] = f2bf1(e[j][nt] * inv);
            }
        }

        short8 pf2[2][2];
#pragma unroll
        for (int mt2 = 0; mt2 < 2; ++mt2)
#pragma unroll
            for (int kc = 0; kc < 2; ++kc)
                pf2[mt2][kc] = *(const short8*)&Pw[(mt2 * 16 + fr) * 68 + kc * 32 + fq * 8];

        f32x4 accO[2][2];
#pragma unroll
        for (int mt2 = 0; mt2 < 2; ++mt2)
#pragma unroll
            for (int ntd = 0; ntd < 2; ++ntd) accO[mt2][ntd] = (f32x4)(0.f);
#pragma unroll
        for (int mt2 = 0; mt2 < 2; ++mt2)
#pragma unroll
            for (int kc = 0; kc < 2; ++kc)
#pragma unroll
                for (int ntd = 0; ntd < 2; ++ntd)
                    accO[mt2][ntd] = __builtin_amdgcn_mfma_f32_16x16x32_bf16(pf2[mt2][kc], avf[ntd][kc], accO[mt2][ntd], 0, 0, 0);

        // fused dwc + bias + bf16 store (C-layout epilogue); V taps via u16x2 spans
        int y = w * 4 + hh;
#pragma unroll
        for (int ntd = 0; ntd < 2; ++ntd) {
            int d = ntd * 16 + fr;
            float wv[9];
#pragma unroll
            for (int t = 0; t < 9; ++t) wv[t] = w9[t][d];
            float bv = bia[d];
            const u16* Vd = &Vt[d * VTP];
#pragma unroll
            for (int mt2 = 0; mt2 < 2; ++mt2) {
                int x0 = mt2 * 16 + fq * 4;
                float sp[3][8];      // tokens x0-2 .. x0+5 per dy row
#pragma unroll
                for (int dy = 0; dy < 3; ++dy) {
                    int yy = y - 1 + dy;
                    if (yy >= 0 && yy < 32) {
                        int base = yy * 32 + x0 - 2;     // even -> 4B-aligned
                        u16x2 r0 = *(const u16x2*)&Vd[base];
                        u16x2 r1 = *(const u16x2*)&Vd[base + 2];
                        u16x2 r2 = *(const u16x2*)&Vd[base + 4];
                        u16x2 r3 = *(const u16x2*)&Vd[base + 6];
                        sp[dy][0] = bf2f(r0[0]); sp[dy][1] = bf2f(r0[1]);
                        sp[dy][2] = bf2f(r1[0]); sp[dy][3] = bf2f(r1[1]);
                        sp[dy][4] = bf2f(r2[0]); sp[dy][5] = bf2f(r2[1]);
                        sp[dy][6] = bf2f(r3[0]); sp[dy][7] = bf2f(r3[1]);
                    } else {
#pragma unroll
                        for (int k = 0; k < 8; ++k) sp[dy][k] = 0.f;
                    }
                }
                float vv[3][6];      // xx = x0-1+k, masked at image edges
#pragma unroll
                for (int dy = 0; dy < 3; ++dy)
#pragma unroll
                    for (int k = 0; k < 6; ++k) {
                        int xx = x0 - 1 + k;
                        vv[dy][k] = (xx >= 0 && xx < 32) ? sp[dy][k + 1] : 0.f;
                    }
#pragma unroll
                for (int j = 0; j < 4; ++j) {
                    float o = accO[mt2][ntd][j] + bv;
#pragma unroll
                    for (int dy = 0; dy < 3; ++dy)
#pragma unroll
                        for (int dx = 0; dx < 3; ++dx)
                            o = fmaf(wv[dy * 3 + dx], vv[dy][j + dx], o);
                    int n = y * 32 + x0 + j;
                    outbf[((size_t)(b * 1025 + 1 + n)) * CH + h * HD + d] = f2bf1(o);
                }
            }
        }
    }
}
#undef VTP

extern "C" void kernel_launch(void* const* d_in, const int* in_sizes, int n_in,
                              void* d_out, int out_size, void* d_ws, size_t ws_size,
                              hipStream_t stream) {
    const float* x      = (const float*)d_in[0];
    const float* qkv_w  = (const float*)d_in[1];
    const float* proj_w = (const float*)d_in[2];
    const float* proj_b = (const float*)d_in[3];
    const float* dwc_w  = (const float*)d_in[4];
    const float* dwc_b  = (const float*)d_in[5];
    const float* an_b   = (const float*)d_in[6];
    const float* ah_b   = (const float*)d_in[7];
    const float* aw_b   = (const float*)d_in[8];
    const float* na_b   = (const float*)d_in[9];
    const float* ha_b   = (const float*)d_in[10];
    const float* wa_b   = (const float*)d_in[11];
    float* out = (float*)d_out;

    float* ws      = (float*)d_ws;
    u16*   qkvb    = (u16*)ws;                 // 25,165,824 u16 (bf16 qkv)
    float* agents  = ws + 12582912;            // 401,408 f
    float* pbn     = agents + 401408;          // 524,288 f  (n-major [h][n][64])
    float* abT     = pbn + 524288;             // 401,408 f  (a-major [h][a][n])
    u16* xbf  = (u16*)(abT + 401408);          // 8,396,800 u16 (x bf16 -> fused bf16 rows)
    u16* qwbf = xbf + 8396800;                 // 196,608 u16
    u16* pwbf = qwbf + 196608;                 // 65,536 u16

    // conversions (xbf rows b*1025 keep bf16 cls tokens for the proj GEMM)
    f2bf_kernel<<<4100, 256, 0, stream>>>(x, xbf, 8396800 / 8);
    f2bf_kernel<<<96, 256, 0, stream>>>(qkv_w, qwbf, 196608 / 8);
    f2bf_kernel<<<32, 256, 0, stream>>>(proj_w, pwbf, 65536 / 8);
    // 1. qkv(bf16) = xs @ qkv_w^T   (M=32768, N=768, K=256)
    gemm_bf16<<<dim3(256, 6), 256, 0, stream>>>(xbf, qwbf, nullptr, qkvb, 32768, 768, 256, nullptr, 1);
    // 2. agent pooling of q
    pool_kernel<<<BATCH * 7, 256, 0, stream>>>(qkvb, agents);
    // 3. position biases (pbn n-major with zero pad rows; abT a-major)
    pb_kernel<<<HEADS * 64, 256, 0, stream>>>(an_b, ah_b, aw_b, pbn);
    ab_kernel<<<(HEADS * AGENTS * NTOK + 255) / 256, 256, 0, stream>>>(na_b, ha_b, wa_b, abT);
    // 4. fused agent-attn + q-attn + dwc -> bf16 rows 1..1024 of xbf
    fused_attn<<<BATCH * HEADS, 512, 0, stream>>>(qkvb, agents, pbn, abT, dwc_w, dwc_b, xbf);
    // 5. out = fused @ proj_w^T + proj_b  (M=32800, N=256, K=256)
    gemm_bf16<<<dim3(257, 2), 256, 0, stream>>>(xbf, pwbf, out, nullptr, 32800, 256, 256, proj_b, 0);
}